// Round 1
// baseline (1525.153 us; speedup 1.0000x reference)
//
#include <hip/hip_runtime.h>
#include <hip/hip_bf16.h>
#include <stdint.h>

#define N_NODES 50000
#define E_EDGES 600000
#define D 128
#define R_REL 8
#define B_BASES 10

typedef __attribute__((ext_vector_type(8))) short bf16x8;
typedef __attribute__((ext_vector_type(4))) float f32x4;

__device__ __forceinline__ short f2b(float f) {
    uint32_t u = __float_as_uint(f);
    u += 0x7fff + ((u >> 16) & 1);   // RNE
    return (short)(u >> 16);
}

// ---- K0a: Wt[r][j][i] = bf16( sum_b comp[r][b] * basis[b][i][j] )  (B-frag layout: [outcol][k]) ----
__global__ __launch_bounds__(256) void k_prep_w(const float* __restrict__ basis,
                                                const float* __restrict__ comp,
                                                short* __restrict__ wt) {
    int tid = blockIdx.x * 256 + threadIdx.x;
    if (tid >= R_REL * D * D) return;
    int r = tid >> 14;
    int rem = tid & 16383;
    int j = rem >> 7;      // out col
    int i = rem & 127;     // k
    float s = 0.f;
#pragma unroll
    for (int b = 0; b < B_BASES; b++)
        s += comp[r * B_BASES + b] * basis[b * D * D + i * D + j];
    wt[tid] = f2b(s);
}

// ---- K0b: root_t[j][i] = root[i][j]; wrel_b/wroot_b direct (already [j][i] for X@W^T) ----
__global__ __launch_bounds__(256) void k_prep_small(const float* __restrict__ root,
                                                    const float* __restrict__ wrel,
                                                    const float* __restrict__ wroot,
                                                    short* __restrict__ root_t,
                                                    short* __restrict__ wrel_b,
                                                    short* __restrict__ wroot_b) {
    int tid = blockIdx.x * 256 + threadIdx.x;
    if (tid >= D * D) return;
    int j = tid >> 7, i = tid & 127;
    root_t[tid]  = f2b(root[i * D + j]);
    wrel_b[tid]  = f2b(wrel[tid]);
    wroot_b[tid] = f2b(wroot[tid]);
}

// ---- K2a: per-(dst,rel) counts + per-rel histogram ----
__global__ __launch_bounds__(256) void k_count(const int* __restrict__ src,
                                               const int* __restrict__ dst,
                                               const int* __restrict__ et,
                                               int* __restrict__ cnt,
                                               int* __restrict__ cnt_rel) {
    __shared__ int lh[R_REL];
    int t = threadIdx.x;
    if (t < R_REL) lh[t] = 0;
    __syncthreads();
    int e = blockIdx.x * 256 + t;
    if (e < E_EDGES) {
        int d = dst[e], r = et[e];
        atomicAdd(&cnt[d * R_REL + r], 1);
        atomicAdd(&lh[r], 1);
    }
    __syncthreads();
    if (t < R_REL && lh[t] > 0) atomicAdd(&cnt_rel[t], lh[t]);
}

// ---- K2p: padded (64-aligned) per-relation offsets; zero cursors ----
__global__ void k_prefix(const int* __restrict__ cnt_rel, int* __restrict__ pad_off,
                         int* __restrict__ cursor) {
    if (threadIdx.x == 0) {
        int acc = 0;
        for (int r = 0; r < R_REL; r++) {
            pad_off[r] = acc;
            acc += (cnt_rel[r] + 63) & ~63;
        }
        pad_off[R_REL] = acc;
    }
    if (threadIdx.x < R_REL) cursor[threadIdx.x] = 0;
}

// ---- K2b: bucket edges by relation, compute per-edge norm ----
__global__ __launch_bounds__(256) void k_scatter_sort(const int* __restrict__ src,
                                                      const int* __restrict__ dst,
                                                      const int* __restrict__ et,
                                                      const int* __restrict__ cnt,
                                                      const int* __restrict__ pad_off,
                                                      int* __restrict__ cursor,
                                                      int* __restrict__ s_src,
                                                      int* __restrict__ s_dst,
                                                      float* __restrict__ s_norm) {
    __shared__ int lh[R_REL];
    __shared__ int lbase[R_REL];
    int t = threadIdx.x;
    if (t < R_REL) lh[t] = 0;
    __syncthreads();
    int e = blockIdx.x * 256 + t;
    bool act = e < E_EDGES;
    int r = 0, lpos = 0, s = 0, d = 0;
    if (act) {
        s = src[e]; d = dst[e]; r = et[e];
        lpos = atomicAdd(&lh[r], 1);
    }
    __syncthreads();
    if (t < R_REL) lbase[t] = lh[t] > 0 ? atomicAdd(&cursor[t], lh[t]) : 0;
    __syncthreads();
    if (act) {
        int idx = pad_off[r] + lbase[r] + lpos;
        s_src[idx] = s;
        s_dst[idx] = d;
        int c = cnt[d * R_REL + r];
        s_norm[idx] = 1.0f / (float)(c > 0 ? c : 1);
    }
}

// ---- K3: per-relation gathered GEMM: msg = x[src] @ W_r, scatter msg*norm into h1 ----
__global__ __launch_bounds__(256) void k_msg_gemm(const float* __restrict__ x,
                                                  const short* __restrict__ wt,
                                                  const int* __restrict__ pad_off,
                                                  const int* __restrict__ s_src,
                                                  const int* __restrict__ s_dst,
                                                  const float* __restrict__ s_norm,
                                                  float* __restrict__ h1) {
    __shared__ short xs[64 * 128];
    __shared__ short ws[128 * 128];
    int base = blockIdx.x * 64;
    if (base >= pad_off[R_REL]) return;
    int r = 0;
    while (base >= pad_off[r + 1]) r++;
    int t = threadIdx.x;

    // stage W_r (16B chunks, XOR-swizzled for bank-balanced b128 reads)
    const uint4* wsrc = (const uint4*)(wt + r * D * D);
    for (int idx = t; idx < 2048; idx += 256) {
        int j = idx >> 4, c = idx & 15;
        *(uint4*)&ws[j * 128 + ((c ^ (j & 15)) << 3)] = wsrc[idx];
    }
    // stage gathered x rows -> bf16
    for (int idx = t; idx < 2048; idx += 256) {
        int row = idx >> 5, q = idx & 31;
        int sidx = s_src[base + row];
        float4 v = make_float4(0.f, 0.f, 0.f, 0.f);
        if (sidx >= 0) v = ((const float4*)(x + (size_t)sidx * D))[q];
        union { uint2 u; short sh[4]; } pk;
        pk.sh[0] = f2b(v.x); pk.sh[1] = f2b(v.y); pk.sh[2] = f2b(v.z); pk.sh[3] = f2b(v.w);
        int chunk = q >> 1, half = q & 1;
        *(uint2*)&xs[row * 128 + ((chunk ^ (row & 15)) << 3) + (half << 2)] = pk.u;
    }
    __syncthreads();

    int wave = t >> 6, lane = t & 63, quad = lane >> 4, l16 = lane & 15;
    f32x4 acc[8];
#pragma unroll
    for (int jt = 0; jt < 8; jt++) acc[jt] = (f32x4){0.f, 0.f, 0.f, 0.f};
#pragma unroll
    for (int kc = 0; kc < 4; kc++) {
        int c0 = kc * 4 + quad;
        bf16x8 a = *(const bf16x8*)&xs[(wave * 16 + l16) * 128 + ((c0 ^ l16) << 3)];
#pragma unroll
        for (int jt = 0; jt < 8; jt++) {
            bf16x8 b = *(const bf16x8*)&ws[(jt * 16 + l16) * 128 + ((c0 ^ l16) << 3)];
            acc[jt] = __builtin_amdgcn_mfma_f32_16x16x32_bf16(a, b, acc[jt], 0, 0, 0);
        }
    }
#pragma unroll
    for (int reg = 0; reg < 4; reg++) {
        int e = base + wave * 16 + quad * 4 + reg;
        int d = s_dst[e];
        if (d < 0) continue;
        float nm = s_norm[e];
        float* hrow = h1 + (size_t)d * D;
#pragma unroll
        for (int jt = 0; jt < 8; jt++)
            atomicAdd(&hrow[jt * 16 + l16], acc[jt][reg] * nm);
    }
}

// ---- K4/K5/K6: out[node] = in[node] @ Bt (+bias) (+prev) ----
__global__ __launch_bounds__(256) void k_node_gemm(const float* __restrict__ in,
                                                   const short* __restrict__ bt,
                                                   const float* __restrict__ bias,
                                                   const float* __restrict__ prev,
                                                   float* __restrict__ out) {
    __shared__ short xs[64 * 128];
    __shared__ short ws[128 * 128];
    int base = blockIdx.x * 64;
    int t = threadIdx.x;
    const uint4* wsrc = (const uint4*)bt;
    for (int idx = t; idx < 2048; idx += 256) {
        int j = idx >> 4, c = idx & 15;
        *(uint4*)&ws[j * 128 + ((c ^ (j & 15)) << 3)] = wsrc[idx];
    }
    for (int idx = t; idx < 2048; idx += 256) {
        int row = idx >> 5, q = idx & 31;
        int node = base + row;
        float4 v = make_float4(0.f, 0.f, 0.f, 0.f);
        if (node < N_NODES) v = ((const float4*)(in + (size_t)node * D))[q];
        union { uint2 u; short sh[4]; } pk;
        pk.sh[0] = f2b(v.x); pk.sh[1] = f2b(v.y); pk.sh[2] = f2b(v.z); pk.sh[3] = f2b(v.w);
        int chunk = q >> 1, half = q & 1;
        *(uint2*)&xs[row * 128 + ((chunk ^ (row & 15)) << 3) + (half << 2)] = pk.u;
    }
    __syncthreads();

    int wave = t >> 6, lane = t & 63, quad = lane >> 4, l16 = lane & 15;
    f32x4 acc[8];
#pragma unroll
    for (int jt = 0; jt < 8; jt++) acc[jt] = (f32x4){0.f, 0.f, 0.f, 0.f};
#pragma unroll
    for (int kc = 0; kc < 4; kc++) {
        int c0 = kc * 4 + quad;
        bf16x8 a = *(const bf16x8*)&xs[(wave * 16 + l16) * 128 + ((c0 ^ l16) << 3)];
#pragma unroll
        for (int jt = 0; jt < 8; jt++) {
            bf16x8 b = *(const bf16x8*)&ws[(jt * 16 + l16) * 128 + ((c0 ^ l16) << 3)];
            acc[jt] = __builtin_amdgcn_mfma_f32_16x16x32_bf16(a, b, acc[jt], 0, 0, 0);
        }
    }
#pragma unroll
    for (int reg = 0; reg < 4; reg++) {
        int node = base + wave * 16 + quad * 4 + reg;
        if (node >= N_NODES) continue;
#pragma unroll
        for (int jt = 0; jt < 8; jt++) {
            int col = jt * 16 + l16;
            float v = acc[jt][reg];
            if (bias) v += bias[col];
            size_t off = (size_t)node * D + col;
            if (prev) v += prev[off];
            out[off] = v;
        }
    }
}

// ---- K7: out[dst] += g[src] per edge ----
__global__ __launch_bounds__(256) void k_graph_scatter(const int* __restrict__ src,
                                                       const int* __restrict__ dst,
                                                       const float* __restrict__ g,
                                                       float* __restrict__ out) {
    int gid = blockIdx.x * 256 + threadIdx.x;
    int e = gid >> 5;
    if (e >= E_EDGES) return;
    int q = gid & 31;
    float4 v = ((const float4*)(g + (size_t)src[e] * D))[q];
    float* orow = out + (size_t)dst[e] * D + q * 4;
    atomicAdd(orow + 0, v.x);
    atomicAdd(orow + 1, v.y);
    atomicAdd(orow + 2, v.z);
    atomicAdd(orow + 3, v.w);
}

extern "C" void kernel_launch(void* const* d_in, const int* in_sizes, int n_in,
                              void* d_out, int out_size, void* d_ws, size_t ws_size,
                              hipStream_t stream) {
    const float* x     = (const float*)d_in[0];
    const int*   ei    = (const int*)d_in[1];
    const int*   et    = (const int*)d_in[2];
    const float* basis = (const float*)d_in[3];
    const float* comp  = (const float*)d_in[4];
    const float* root  = (const float*)d_in[5];
    const float* bias1 = (const float*)d_in[6];
    const float* wrel  = (const float*)d_in[7];
    const float* brel  = (const float*)d_in[8];
    const float* wroot = (const float*)d_in[9];
    float* out = (float*)d_out;
    const int* src = ei;
    const int* dst = ei + E_EDGES;

    char* p = (char*)d_ws;
    auto alloc = [&](size_t bytes) { char* q = p; p += (bytes + 255) & ~(size_t)255; return q; };
    short* wt      = (short*)alloc((size_t)R_REL * D * D * sizeof(short));
    short* root_t  = (short*)alloc(D * D * sizeof(short));
    short* wrel_b  = (short*)alloc(D * D * sizeof(short));
    short* wroot_b = (short*)alloc(D * D * sizeof(short));
    int*   cnt     = (int*)alloc((size_t)N_NODES * R_REL * sizeof(int));
    int*   cnt_rel = (int*)alloc(R_REL * sizeof(int));
    int*   pad_off = (int*)alloc((R_REL + 1) * sizeof(int));
    int*   cursor  = (int*)alloc(R_REL * sizeof(int));
    const int EPAD = E_EDGES + R_REL * 64;
    int*   s_src   = (int*)alloc((size_t)EPAD * sizeof(int));
    int*   s_dst   = (int*)alloc((size_t)EPAD * sizeof(int));
    float* s_norm  = (float*)alloc((size_t)EPAD * sizeof(float));
    float* h1      = (float*)alloc((size_t)N_NODES * D * sizeof(float));
    float* g       = (float*)alloc((size_t)N_NODES * D * sizeof(float));

    hipMemsetAsync(cnt, 0, (size_t)N_NODES * R_REL * sizeof(int), stream);
    hipMemsetAsync(cnt_rel, 0, R_REL * sizeof(int), stream);
    hipMemsetAsync(h1, 0, (size_t)N_NODES * D * sizeof(float), stream);
    hipMemsetAsync(s_src, 0xFF, (size_t)EPAD * sizeof(int), stream);
    hipMemsetAsync(s_dst, 0xFF, (size_t)EPAD * sizeof(int), stream);

    k_prep_w<<<(R_REL * D * D + 255) / 256, 256, 0, stream>>>(basis, comp, wt);
    k_prep_small<<<(D * D + 255) / 256, 256, 0, stream>>>(root, wrel, wroot, root_t, wrel_b, wroot_b);
    k_count<<<(E_EDGES + 255) / 256, 256, 0, stream>>>(src, dst, et, cnt, cnt_rel);
    k_prefix<<<1, 64, 0, stream>>>(cnt_rel, pad_off, cursor);
    k_scatter_sort<<<(E_EDGES + 255) / 256, 256, 0, stream>>>(src, dst, et, cnt, pad_off, cursor,
                                                              s_src, s_dst, s_norm);
    int nt = (E_EDGES + 63) / 64 + R_REL;
    k_msg_gemm<<<nt, 256, 0, stream>>>(x, wt, pad_off, s_src, s_dst, s_norm, h1);
    int nb = (N_NODES + 63) / 64;
    k_node_gemm<<<nb, 256, 0, stream>>>(x, root_t, bias1, h1, h1);       // h1 = agg + x@root + bias1
    k_node_gemm<<<nb, 256, 0, stream>>>(h1, wrel_b, nullptr, nullptr, g); // g = h1 @ w_rel^T
    k_node_gemm<<<nb, 256, 0, stream>>>(h1, wroot_b, brel, nullptr, out); // out = h1 @ w_root^T + b_rel
    k_graph_scatter<<<(E_EDGES * 32 + 255) / 256, 256, 0, stream>>>(src, dst, g, out);
}

// Round 2
// 635.955 us; speedup vs baseline: 2.3982x; 2.3982x over previous
//
#include <hip/hip_runtime.h>
#include <stdint.h>

#define N_NODES 50000
#define E_EDGES 600000
#define D 128
#define R_REL 8
#define B_BASES 10
#define RN (R_REL * N_NODES)
#define SCAN_B 1024

typedef __attribute__((ext_vector_type(8))) short bf16x8;
typedef __attribute__((ext_vector_type(4))) float f32x4;

__device__ __forceinline__ short f2b(float f) {
    uint32_t u = __float_as_uint(f);
    u += 0x7fff + ((u >> 16) & 1);   // RNE
    return (short)(u >> 16);
}
__device__ __forceinline__ float b2f(uint16_t u) {
    return __uint_as_float((uint32_t)u << 16);
}

// ---- Wt[r][j][i] = bf16( sum_b comp[r][b] * basis[b][i][j] )  (B-frag layout [outcol][k]) ----
__global__ __launch_bounds__(256) void k_prep_w(const float* __restrict__ basis,
                                                const float* __restrict__ comp,
                                                short* __restrict__ wt) {
    int tid = blockIdx.x * 256 + threadIdx.x;
    if (tid >= R_REL * D * D) return;
    int r = tid >> 14;
    int rem = tid & 16383;
    int j = rem >> 7;      // out col
    int i = rem & 127;     // k
    float s = 0.f;
#pragma unroll
    for (int b = 0; b < B_BASES; b++)
        s += comp[r * B_BASES + b] * basis[b * D * D + i * D + j];
    wt[tid] = f2b(s);
}

__global__ __launch_bounds__(256) void k_prep_small(const float* __restrict__ root,
                                                    const float* __restrict__ wrel,
                                                    const float* __restrict__ wroot,
                                                    short* __restrict__ root_t,
                                                    short* __restrict__ wrel_b,
                                                    short* __restrict__ wroot_b) {
    int tid = blockIdx.x * 256 + threadIdx.x;
    if (tid >= D * D) return;
    int j = tid >> 7, i = tid & 127;
    root_t[tid]  = f2b(root[i * D + j]);   // B[j][k] = root[k][j]
    wrel_b[tid]  = f2b(wrel[tid]);         // B[j][k] = w_rel[j][k]
    wroot_b[tid] = f2b(wroot[tid]);
}

// ---- histogram per (rel, dst) ----
__global__ __launch_bounds__(256) void k_count(const int* __restrict__ dst,
                                               const int* __restrict__ et,
                                               int* __restrict__ cntr) {
    int e = blockIdx.x * 256 + threadIdx.x;
    if (e >= E_EDGES) return;
    atomicAdd(&cntr[et[e] * N_NODES + dst[e]], 1);
}

// ---- 3-kernel exclusive scan ----
__global__ __launch_bounds__(SCAN_B) void k_scan_a(const int* __restrict__ in,
                                                   int* __restrict__ out,
                                                   int* __restrict__ bsum, int n) {
    __shared__ int lds[SCAN_B];
    int t = threadIdx.x, g = blockIdx.x * SCAN_B + t;
    int v = (g < n) ? in[g] : 0;
    lds[t] = v;
    __syncthreads();
    for (int off = 1; off < SCAN_B; off <<= 1) {
        int tv = (t >= off) ? lds[t - off] : 0;
        __syncthreads();
        lds[t] += tv;
        __syncthreads();
    }
    if (g < n) out[g] = lds[t] - v;
    if (t == SCAN_B - 1) bsum[blockIdx.x] = lds[t];
}

__global__ __launch_bounds__(SCAN_B) void k_scan_b(int* __restrict__ bsum, int nb) {
    __shared__ int lds[SCAN_B];
    int t = threadIdx.x;
    int v = (t < nb) ? bsum[t] : 0;
    lds[t] = v;
    __syncthreads();
    for (int off = 1; off < SCAN_B; off <<= 1) {
        int tv = (t >= off) ? lds[t - off] : 0;
        __syncthreads();
        lds[t] += tv;
        __syncthreads();
    }
    if (t < nb) bsum[t] = lds[t] - v;
}

__global__ __launch_bounds__(SCAN_B) void k_scan_c(int* __restrict__ out,
                                                   const int* __restrict__ bsum, int n) {
    int g = blockIdx.x * SCAN_B + threadIdx.x;
    if (g < n) out[g] += bsum[blockIdx.x];
}

// ---- bucket edges into (rel,dst)-sorted order ----
__global__ __launch_bounds__(256) void k_bucket(const int* __restrict__ src,
                                                const int* __restrict__ dst,
                                                const int* __restrict__ et,
                                                const int* __restrict__ seg_off,
                                                int* __restrict__ cur,
                                                int* __restrict__ es1) {
    int e = blockIdx.x * 256 + threadIdx.x;
    if (e >= E_EDGES) return;
    int key = et[e] * N_NODES + dst[e];
    int pos = seg_off[key] + atomicAdd(&cur[key], 1);
    es1[pos] = src[e];
}

// ---- tiled MFMA GEMM: out = in @ Bt (+bias) (+prev); in/out either fp32 or bf16 ----
__global__ __launch_bounds__(256) void k_gemm(const float* __restrict__ inf,
                                              const unsigned short* __restrict__ inb,
                                              const short* __restrict__ bt,
                                              const float* __restrict__ bias,
                                              const float* __restrict__ prev,
                                              float* __restrict__ outf,
                                              unsigned short* __restrict__ outb) {
    __shared__ short xs[64 * 128];
    __shared__ short ws[128 * 128];
    int base = blockIdx.x * 64;
    int t = threadIdx.x;
    const uint4* wsrc = (const uint4*)bt;
    for (int idx = t; idx < 2048; idx += 256) {
        int j = idx >> 4, c = idx & 15;
        *(uint4*)&ws[j * 128 + ((c ^ (j & 15)) << 3)] = wsrc[idx];
    }
    if (inb) {
        for (int idx = t; idx < 1024; idx += 256) {
            int row = idx >> 4, c = idx & 15;
            int node = base + row;
            uint4 v = make_uint4(0, 0, 0, 0);
            if (node < N_NODES) v = ((const uint4*)(inb + (size_t)node * D))[c];
            *(uint4*)&xs[row * 128 + ((c ^ (row & 15)) << 3)] = v;
        }
    } else {
        for (int idx = t; idx < 2048; idx += 256) {
            int row = idx >> 5, q = idx & 31;
            int node = base + row;
            float4 v = make_float4(0.f, 0.f, 0.f, 0.f);
            if (node < N_NODES) v = ((const float4*)(inf + (size_t)node * D))[q];
            union { uint2 u; short sh[4]; } pk;
            pk.sh[0] = f2b(v.x); pk.sh[1] = f2b(v.y); pk.sh[2] = f2b(v.z); pk.sh[3] = f2b(v.w);
            int chunk = q >> 1, half = q & 1;
            *(uint2*)&xs[row * 128 + ((chunk ^ (row & 15)) << 3) + (half << 2)] = pk.u;
        }
    }
    __syncthreads();

    int wave = t >> 6, lane = t & 63, quad = lane >> 4, l16 = lane & 15;
    f32x4 acc[8];
#pragma unroll
    for (int jt = 0; jt < 8; jt++) acc[jt] = (f32x4){0.f, 0.f, 0.f, 0.f};
#pragma unroll
    for (int kc = 0; kc < 4; kc++) {
        int c0 = kc * 4 + quad;
        bf16x8 a = *(const bf16x8*)&xs[(wave * 16 + l16) * 128 + ((c0 ^ l16) << 3)];
#pragma unroll
        for (int jt = 0; jt < 8; jt++) {
            bf16x8 b = *(const bf16x8*)&ws[(jt * 16 + l16) * 128 + ((c0 ^ l16) << 3)];
            acc[jt] = __builtin_amdgcn_mfma_f32_16x16x32_bf16(a, b, acc[jt], 0, 0, 0);
        }
    }
#pragma unroll
    for (int reg = 0; reg < 4; reg++) {
        int node = base + wave * 16 + quad * 4 + reg;
        if (node >= N_NODES) continue;
#pragma unroll
        for (int jt = 0; jt < 8; jt++) {
            int col = jt * 16 + l16;
            float v = acc[jt][reg];
            if (bias) v += bias[col];
            size_t off = (size_t)node * D + col;
            if (prev) v += prev[off];
            if (outf) outf[off] = v;
            else outb[off] = (unsigned short)f2b(v);
        }
    }
}

// ---- RGCN aggregation, relation r: h1[d] += (1/cnt) * sum y[src] (owner-exclusive) ----
__global__ __launch_bounds__(256) void k_agg_h1(const unsigned short* __restrict__ y,
                                                const int* __restrict__ es1,
                                                const int* __restrict__ cntr,
                                                const int* __restrict__ seg_off,
                                                float* __restrict__ h1, int r) {
    int wid = (blockIdx.x * 256 + threadIdx.x) >> 6;
    if (wid >= N_NODES) return;
    int lane = threadIdx.x & 63;
    int c = cntr[r * N_NODES + wid];
    if (c == 0) return;
    int s0 = seg_off[r * N_NODES + wid];
    float ax = 0.f, ay = 0.f;
    for (int i = 0; i < c; i++) {
        int s = es1[s0 + i];
        uint32_t v = *(const uint32_t*)(y + (size_t)s * D + lane * 2);
        ax += b2f((uint16_t)v);
        ay += b2f((uint16_t)(v >> 16));
    }
    float nm = 1.f / (float)c;
    float* hr = h1 + (size_t)wid * D + lane * 2;
    hr[0] += nm * ax;
    hr[1] += nm * ay;
}

// ---- GraphConv aggregation: nbr[d] = sum over all relations of h1[src]  (bf16 out) ----
__global__ __launch_bounds__(256) void k_agg_nbr(const float* __restrict__ h1,
                                                 const int* __restrict__ es1,
                                                 const int* __restrict__ cntr,
                                                 const int* __restrict__ seg_off,
                                                 unsigned short* __restrict__ nbr) {
    int wid = (blockIdx.x * 256 + threadIdx.x) >> 6;
    if (wid >= N_NODES) return;
    int lane = threadIdx.x & 63;
    float ax = 0.f, ay = 0.f;
    for (int r = 0; r < R_REL; r++) {
        int c = cntr[r * N_NODES + wid];
        if (c == 0) continue;
        int s0 = seg_off[r * N_NODES + wid];
        for (int i = 0; i < c; i++) {
            int s = es1[s0 + i];
            float2 v = *(const float2*)(h1 + (size_t)s * D + lane * 2);
            ax += v.x;
            ay += v.y;
        }
    }
    uint32_t lo = (uint16_t)f2b(ax), hi = (uint16_t)f2b(ay);
    *(uint32_t*)(nbr + (size_t)wid * D + lane * 2) = lo | (hi << 16);
}

extern "C" void kernel_launch(void* const* d_in, const int* in_sizes, int n_in,
                              void* d_out, int out_size, void* d_ws, size_t ws_size,
                              hipStream_t stream) {
    const float* x     = (const float*)d_in[0];
    const int*   ei    = (const int*)d_in[1];
    const int*   et    = (const int*)d_in[2];
    const float* basis = (const float*)d_in[3];
    const float* comp  = (const float*)d_in[4];
    const float* root  = (const float*)d_in[5];
    const float* bias1 = (const float*)d_in[6];
    const float* wrel  = (const float*)d_in[7];
    const float* brel  = (const float*)d_in[8];
    const float* wroot = (const float*)d_in[9];
    float* out = (float*)d_out;
    const int* src = ei;
    const int* dst = ei + E_EDGES;

    char* p = (char*)d_ws;
    auto alloc = [&](size_t bytes) { char* q = p; p += (bytes + 255) & ~(size_t)255; return q; };
    short* wt      = (short*)alloc((size_t)R_REL * D * D * sizeof(short));
    short* root_t  = (short*)alloc(D * D * sizeof(short));
    short* wrel_b  = (short*)alloc(D * D * sizeof(short));
    short* wroot_b = (short*)alloc(D * D * sizeof(short));
    int*   cntr    = (int*)alloc((size_t)RN * sizeof(int));
    int*   seg_off = (int*)alloc((size_t)RN * sizeof(int));
    int*   cur     = (int*)alloc((size_t)RN * sizeof(int));
    int*   es1     = (int*)alloc((size_t)E_EDGES * sizeof(int));
    int*   bsum    = (int*)alloc(SCAN_B * sizeof(int));
    unsigned short* ybuf = (unsigned short*)alloc((size_t)N_NODES * D * sizeof(unsigned short));
    float* h1      = (float*)alloc((size_t)N_NODES * D * sizeof(float));

    hipMemsetAsync(cntr, 0, (size_t)RN * sizeof(int), stream);
    hipMemsetAsync(cur,  0, (size_t)RN * sizeof(int), stream);

    k_prep_w<<<(R_REL * D * D + 255) / 256, 256, 0, stream>>>(basis, comp, wt);
    k_prep_small<<<(D * D + 255) / 256, 256, 0, stream>>>(root, wrel, wroot, root_t, wrel_b, wroot_b);
    k_count<<<(E_EDGES + 255) / 256, 256, 0, stream>>>(dst, et, cntr);

    int nscan = (RN + SCAN_B - 1) / SCAN_B;   // 391
    k_scan_a<<<nscan, SCAN_B, 0, stream>>>(cntr, seg_off, bsum, RN);
    k_scan_b<<<1, SCAN_B, 0, stream>>>(bsum, nscan);
    k_scan_c<<<nscan, SCAN_B, 0, stream>>>(seg_off, bsum, RN);

    k_bucket<<<(E_EDGES + 255) / 256, 256, 0, stream>>>(src, dst, et, seg_off, cur, es1);

    int nb = (N_NODES + 63) / 64;             // 782
    int na = (N_NODES + 3) / 4;               // 12500 blocks (4 waves each)

    // h1 = x @ root + bias1
    k_gemm<<<nb, 256, 0, stream>>>(x, nullptr, root_t, bias1, nullptr, h1, nullptr);
    // h1 += per-relation mean aggregation of y_r[src]
    for (int r = 0; r < R_REL; r++) {
        k_gemm<<<nb, 256, 0, stream>>>(x, nullptr, wt + (size_t)r * D * D, nullptr, nullptr,
                                       nullptr, ybuf);
        k_agg_h1<<<na, 256, 0, stream>>>(ybuf, es1, cntr, seg_off, h1, r);
    }
    // nbr (bf16, reusing ybuf) = sum h1[src]
    k_agg_nbr<<<na, 256, 0, stream>>>(h1, es1, cntr, seg_off, ybuf);
    // out = h1 @ w_root^T
    k_gemm<<<nb, 256, 0, stream>>>(h1, nullptr, wroot_b, nullptr, nullptr, out, nullptr);
    // out += nbr @ w_rel^T + b_rel
    k_gemm<<<nb, 256, 0, stream>>>(nullptr, ybuf, wrel_b, brel, out, out, nullptr);
}

// Round 3
// 432.419 us; speedup vs baseline: 3.5270x; 1.4707x over previous
//
#include <hip/hip_runtime.h>
#include <stdint.h>

#define N_NODES 50000
#define E_EDGES 600000
#define D 128
#define R_REL 8
#define B_BASES 10
#define RN (R_REL * N_NODES)
#define SCAN_B 1024

typedef __attribute__((ext_vector_type(8))) short bf16x8;
typedef __attribute__((ext_vector_type(4))) float f32x4;

__device__ __forceinline__ short f2b(float f) {
    uint32_t u = __float_as_uint(f);
    u += 0x7fff + ((u >> 16) & 1);   // RNE
    return (short)(u >> 16);
}
__device__ __forceinline__ float b2f(uint16_t u) {
    return __uint_as_float((uint32_t)u << 16);
}

// ---- fused weight prep: wt[r][j][i] = sum_b comp[r][b]*basis[b][i][j]; small mats ----
__global__ __launch_bounds__(256) void k_prep(const float* __restrict__ basis,
                                              const float* __restrict__ comp,
                                              const float* __restrict__ root,
                                              const float* __restrict__ wrel,
                                              const float* __restrict__ wroot,
                                              short* __restrict__ wt,
                                              short* __restrict__ root_t,
                                              short* __restrict__ wrel_b,
                                              short* __restrict__ wroot_b) {
    int tid = blockIdx.x * 256 + threadIdx.x;
    if (tid < R_REL * D * D) {
        int r = tid >> 14;
        int rem = tid & 16383;
        int j = rem >> 7, i = rem & 127;
        float s = 0.f;
#pragma unroll
        for (int b = 0; b < B_BASES; b++)
            s += comp[r * B_BASES + b] * basis[b * D * D + i * D + j];
        wt[tid] = f2b(s);
    } else {
        int t2 = tid - R_REL * D * D;
        if (t2 < D * D) {
            int j = t2 >> 7, i = t2 & 127;
            root_t[t2]  = f2b(root[i * D + j]);
            wrel_b[t2]  = f2b(wrel[t2]);
            wroot_b[t2] = f2b(wroot[t2]);
        }
    }
}

// ---- x (fp32) -> xb (bf16), 8 elems/thread ----
__global__ __launch_bounds__(256) void k_x2b(const float* __restrict__ x,
                                             unsigned short* __restrict__ xb) {
    int tid = blockIdx.x * 256 + threadIdx.x;
    if (tid >= N_NODES * D / 8) return;
    const float4* s = (const float4*)x + (size_t)tid * 2;
    float4 v0 = s[0], v1 = s[1];
    union { uint4 u; unsigned short h[8]; } pk;
    pk.h[0] = (unsigned short)f2b(v0.x); pk.h[1] = (unsigned short)f2b(v0.y);
    pk.h[2] = (unsigned short)f2b(v0.z); pk.h[3] = (unsigned short)f2b(v0.w);
    pk.h[4] = (unsigned short)f2b(v1.x); pk.h[5] = (unsigned short)f2b(v1.y);
    pk.h[6] = (unsigned short)f2b(v1.z); pk.h[7] = (unsigned short)f2b(v1.w);
    ((uint4*)xb)[tid] = pk.u;
}

// ---- histogram per (rel, dst) ----
__global__ __launch_bounds__(256) void k_count(const int* __restrict__ dst,
                                               const int* __restrict__ et,
                                               int* __restrict__ cntr) {
    int e = blockIdx.x * 256 + threadIdx.x;
    if (e >= E_EDGES) return;
    atomicAdd(&cntr[et[e] * N_NODES + dst[e]], 1);
}

// ---- 3-kernel exclusive scan ----
__global__ __launch_bounds__(SCAN_B) void k_scan_a(const int* __restrict__ in,
                                                   int* __restrict__ out,
                                                   int* __restrict__ bsum, int n) {
    __shared__ int lds[SCAN_B];
    int t = threadIdx.x, g = blockIdx.x * SCAN_B + t;
    int v = (g < n) ? in[g] : 0;
    lds[t] = v;
    __syncthreads();
    for (int off = 1; off < SCAN_B; off <<= 1) {
        int tv = (t >= off) ? lds[t - off] : 0;
        __syncthreads();
        lds[t] += tv;
        __syncthreads();
    }
    if (g < n) out[g] = lds[t] - v;
    if (t == SCAN_B - 1) bsum[blockIdx.x] = lds[t];
}

__global__ __launch_bounds__(SCAN_B) void k_scan_b(int* __restrict__ bsum, int nb) {
    __shared__ int lds[SCAN_B];
    int t = threadIdx.x;
    int v = (t < nb) ? bsum[t] : 0;
    lds[t] = v;
    __syncthreads();
    for (int off = 1; off < SCAN_B; off <<= 1) {
        int tv = (t >= off) ? lds[t - off] : 0;
        __syncthreads();
        lds[t] += tv;
        __syncthreads();
    }
    if (t < nb) bsum[t] = lds[t] - v;
}

__global__ __launch_bounds__(SCAN_B) void k_scan_c(int* __restrict__ out,
                                                   const int* __restrict__ bsum, int n) {
    int g = blockIdx.x * SCAN_B + threadIdx.x;
    if (g < n) out[g] += bsum[blockIdx.x];
}

// ---- bucket edges into (rel,dst)-sorted order ----
__global__ __launch_bounds__(256) void k_bucket(const int* __restrict__ src,
                                                const int* __restrict__ dst,
                                                const int* __restrict__ et,
                                                const int* __restrict__ seg_off,
                                                int* __restrict__ cur,
                                                int* __restrict__ es1) {
    int e = blockIdx.x * 256 + threadIdx.x;
    if (e >= E_EDGES) return;
    int key = et[e] * N_NODES + dst[e];
    int pos = seg_off[key] + atomicAdd(&cur[key], 1);
    es1[pos] = src[e];
}

// ---- batched per-relation GEMM: ybig[slice] = xb @ W_{r0+slice}  (grid.y slices) ----
__global__ __launch_bounds__(256) void k_ygemm(const unsigned short* __restrict__ xb,
                                               const short* __restrict__ wt, int r0,
                                               unsigned short* __restrict__ ybig) {
    __shared__ short xs[64 * 128];
    __shared__ short ws[128 * 128];
    int slice = blockIdx.y;
    const short* w = wt + (size_t)(r0 + slice) * D * D;
    unsigned short* y = ybig + (size_t)slice * N_NODES * D;
    int base = blockIdx.x * 64;
    int t = threadIdx.x;
    const uint4* wsrc = (const uint4*)w;
    for (int idx = t; idx < 2048; idx += 256) {
        int j = idx >> 4, c = idx & 15;
        *(uint4*)&ws[j * 128 + ((c ^ (j & 15)) << 3)] = wsrc[idx];
    }
    for (int idx = t; idx < 1024; idx += 256) {
        int row = idx >> 4, c = idx & 15;
        int node = base + row;
        uint4 v = make_uint4(0, 0, 0, 0);
        if (node < N_NODES) v = ((const uint4*)(xb + (size_t)node * D))[c];
        *(uint4*)&xs[row * 128 + ((c ^ (row & 15)) << 3)] = v;
    }
    __syncthreads();

    int wave = t >> 6, lane = t & 63, quad = lane >> 4, l16 = lane & 15;
    f32x4 acc[8];
#pragma unroll
    for (int jt = 0; jt < 8; jt++) acc[jt] = (f32x4){0.f, 0.f, 0.f, 0.f};
#pragma unroll
    for (int kc = 0; kc < 4; kc++) {
        int c0 = kc * 4 + quad;
        bf16x8 a = *(const bf16x8*)&xs[(wave * 16 + l16) * 128 + ((c0 ^ l16) << 3)];
#pragma unroll
        for (int jt = 0; jt < 8; jt++) {
            bf16x8 b = *(const bf16x8*)&ws[(jt * 16 + l16) * 128 + ((c0 ^ l16) << 3)];
            acc[jt] = __builtin_amdgcn_mfma_f32_16x16x32_bf16(a, b, acc[jt], 0, 0, 0);
        }
    }
#pragma unroll
    for (int reg = 0; reg < 4; reg++) {
        int node = base + wave * 16 + quad * 4 + reg;
        if (node >= N_NODES) continue;
#pragma unroll
        for (int jt = 0; jt < 8; jt++)
            y[(size_t)node * D + jt * 16 + l16] = (unsigned short)f2b(acc[jt][reg]);
    }
}

// ---- generic GEMM (bf16 in, fp32 prev add, bf16 out) for the root transform ----
__global__ __launch_bounds__(256) void k_gemm_root(const unsigned short* __restrict__ inb,
                                                   const short* __restrict__ bt,
                                                   const float* __restrict__ bias,
                                                   const float* __restrict__ prev,
                                                   unsigned short* __restrict__ outb) {
    __shared__ short xs[64 * 128];
    __shared__ short ws[128 * 128];
    int base = blockIdx.x * 64;
    int t = threadIdx.x;
    const uint4* wsrc = (const uint4*)bt;
    for (int idx = t; idx < 2048; idx += 256) {
        int j = idx >> 4, c = idx & 15;
        *(uint4*)&ws[j * 128 + ((c ^ (j & 15)) << 3)] = wsrc[idx];
    }
    for (int idx = t; idx < 1024; idx += 256) {
        int row = idx >> 4, c = idx & 15;
        int node = base + row;
        uint4 v = make_uint4(0, 0, 0, 0);
        if (node < N_NODES) v = ((const uint4*)(inb + (size_t)node * D))[c];
        *(uint4*)&xs[row * 128 + ((c ^ (row & 15)) << 3)] = v;
    }
    __syncthreads();

    int wave = t >> 6, lane = t & 63, quad = lane >> 4, l16 = lane & 15;
    f32x4 acc[8];
#pragma unroll
    for (int jt = 0; jt < 8; jt++) acc[jt] = (f32x4){0.f, 0.f, 0.f, 0.f};
#pragma unroll
    for (int kc = 0; kc < 4; kc++) {
        int c0 = kc * 4 + quad;
        bf16x8 a = *(const bf16x8*)&xs[(wave * 16 + l16) * 128 + ((c0 ^ l16) << 3)];
#pragma unroll
        for (int jt = 0; jt < 8; jt++) {
            bf16x8 b = *(const bf16x8*)&ws[(jt * 16 + l16) * 128 + ((c0 ^ l16) << 3)];
            acc[jt] = __builtin_amdgcn_mfma_f32_16x16x32_bf16(a, b, acc[jt], 0, 0, 0);
        }
    }
#pragma unroll
    for (int reg = 0; reg < 4; reg++) {
        int node = base + wave * 16 + quad * 4 + reg;
        if (node >= N_NODES) continue;
#pragma unroll
        for (int jt = 0; jt < 8; jt++) {
            int col = jt * 16 + l16;
            float v = acc[jt][reg] + bias[col] + prev[(size_t)node * D + col];
            outb[(size_t)node * D + col] = (unsigned short)f2b(v);
        }
    }
}

// ---- RGCN aggregation over 4 relations (one wave per dst), unroll-4 gather ----
__global__ __launch_bounds__(256) void k_agg4(const unsigned short* __restrict__ y,
                                              const int* __restrict__ es1,
                                              const int* __restrict__ cntr,
                                              const int* __restrict__ seg_off,
                                              float* __restrict__ h1, int r0, int accum) {
    int wid = (blockIdx.x * 256 + threadIdx.x) >> 6;
    if (wid >= N_NODES) return;
    int lane = threadIdx.x & 63;
    int off2 = lane * 2;
    float tx = 0.f, ty = 0.f;
#pragma unroll
    for (int rr = 0; rr < 4; rr++) {
        int key = (r0 + rr) * N_NODES + wid;
        int c = cntr[key];
        if (c == 0) continue;
        int s0 = seg_off[key];
        const unsigned short* yb = y + (size_t)rr * N_NODES * D;
        float sx = 0.f, sy = 0.f;
        int i = 0;
        for (; i + 4 <= c; i += 4) {
            int a0 = es1[s0 + i], a1 = es1[s0 + i + 1];
            int a2 = es1[s0 + i + 2], a3 = es1[s0 + i + 3];
            uint32_t v0 = *(const uint32_t*)(yb + (size_t)a0 * D + off2);
            uint32_t v1 = *(const uint32_t*)(yb + (size_t)a1 * D + off2);
            uint32_t v2 = *(const uint32_t*)(yb + (size_t)a2 * D + off2);
            uint32_t v3 = *(const uint32_t*)(yb + (size_t)a3 * D + off2);
            sx += b2f((uint16_t)v0) + b2f((uint16_t)v1) + b2f((uint16_t)v2) + b2f((uint16_t)v3);
            sy += b2f((uint16_t)(v0 >> 16)) + b2f((uint16_t)(v1 >> 16)) +
                  b2f((uint16_t)(v2 >> 16)) + b2f((uint16_t)(v3 >> 16));
        }
        for (; i < c; i++) {
            int a0 = es1[s0 + i];
            uint32_t v0 = *(const uint32_t*)(yb + (size_t)a0 * D + off2);
            sx += b2f((uint16_t)v0);
            sy += b2f((uint16_t)(v0 >> 16));
        }
        float nm = 1.f / (float)c;
        tx += nm * sx;
        ty += nm * sy;
    }
    float* hr = h1 + (size_t)wid * D + off2;
    if (accum) { tx += hr[0]; ty += hr[1]; }
    hr[0] = tx;
    hr[1] = ty;
}

// ---- GraphConv aggregation: nbr[d] = sum_{r,e} h1b[src], bf16 gather, unroll-4 ----
__global__ __launch_bounds__(256) void k_agg_nbr(const unsigned short* __restrict__ h1b,
                                                 const int* __restrict__ es1,
                                                 const int* __restrict__ cntr,
                                                 const int* __restrict__ seg_off,
                                                 unsigned short* __restrict__ nbr) {
    int wid = (blockIdx.x * 256 + threadIdx.x) >> 6;
    if (wid >= N_NODES) return;
    int lane = threadIdx.x & 63;
    int off2 = lane * 2;
    float tx = 0.f, ty = 0.f;
#pragma unroll
    for (int r = 0; r < R_REL; r++) {
        int key = r * N_NODES + wid;
        int c = cntr[key];
        if (c == 0) continue;
        int s0 = seg_off[key];
        int i = 0;
        for (; i + 4 <= c; i += 4) {
            int a0 = es1[s0 + i], a1 = es1[s0 + i + 1];
            int a2 = es1[s0 + i + 2], a3 = es1[s0 + i + 3];
            uint32_t v0 = *(const uint32_t*)(h1b + (size_t)a0 * D + off2);
            uint32_t v1 = *(const uint32_t*)(h1b + (size_t)a1 * D + off2);
            uint32_t v2 = *(const uint32_t*)(h1b + (size_t)a2 * D + off2);
            uint32_t v3 = *(const uint32_t*)(h1b + (size_t)a3 * D + off2);
            tx += b2f((uint16_t)v0) + b2f((uint16_t)v1) + b2f((uint16_t)v2) + b2f((uint16_t)v3);
            ty += b2f((uint16_t)(v0 >> 16)) + b2f((uint16_t)(v1 >> 16)) +
                  b2f((uint16_t)(v2 >> 16)) + b2f((uint16_t)(v3 >> 16));
        }
        for (; i < c; i++) {
            int a0 = es1[s0 + i];
            uint32_t v0 = *(const uint32_t*)(h1b + (size_t)a0 * D + off2);
            tx += b2f((uint16_t)v0);
            ty += b2f((uint16_t)(v0 >> 16));
        }
    }
    uint32_t lo = (uint16_t)f2b(tx), hi = (uint16_t)f2b(ty);
    *(uint32_t*)(nbr + (size_t)wid * D + off2) = lo | (hi << 16);
}

// ---- fused epilogue: out = h1b @ wroot^T + nbr @ wrel^T + brel ----
__global__ __launch_bounds__(256) void k_out2(const unsigned short* __restrict__ h1b,
                                              const unsigned short* __restrict__ nbr,
                                              const short* __restrict__ wroot_b,
                                              const short* __restrict__ wrel_b,
                                              const float* __restrict__ brel,
                                              float* __restrict__ out) {
    __shared__ short xs1[64 * 128];
    __shared__ short xs2[64 * 128];
    __shared__ short ws1[128 * 128];
    __shared__ short ws2[128 * 128];
    int base = blockIdx.x * 64;
    int t = threadIdx.x;
    const uint4* w1 = (const uint4*)wroot_b;
    const uint4* w2 = (const uint4*)wrel_b;
    for (int idx = t; idx < 2048; idx += 256) {
        int j = idx >> 4, c = idx & 15;
        int sw = j * 128 + ((c ^ (j & 15)) << 3);
        *(uint4*)&ws1[sw] = w1[idx];
        *(uint4*)&ws2[sw] = w2[idx];
    }
    for (int idx = t; idx < 1024; idx += 256) {
        int row = idx >> 4, c = idx & 15;
        int node = base + row;
        uint4 v1 = make_uint4(0, 0, 0, 0), v2 = make_uint4(0, 0, 0, 0);
        if (node < N_NODES) {
            v1 = ((const uint4*)(h1b + (size_t)node * D))[c];
            v2 = ((const uint4*)(nbr + (size_t)node * D))[c];
        }
        int sw = row * 128 + ((c ^ (row & 15)) << 3);
        *(uint4*)&xs1[sw] = v1;
        *(uint4*)&xs2[sw] = v2;
    }
    __syncthreads();

    int wave = t >> 6, lane = t & 63, quad = lane >> 4, l16 = lane & 15;
    f32x4 acc[8];
#pragma unroll
    for (int jt = 0; jt < 8; jt++) acc[jt] = (f32x4){0.f, 0.f, 0.f, 0.f};
#pragma unroll
    for (int kc = 0; kc < 4; kc++) {
        int c0 = kc * 4 + quad;
        int arow = (wave * 16 + l16) * 128 + ((c0 ^ l16) << 3);
        bf16x8 a1 = *(const bf16x8*)&xs1[arow];
        bf16x8 a2 = *(const bf16x8*)&xs2[arow];
#pragma unroll
        for (int jt = 0; jt < 8; jt++) {
            int brow = (jt * 16 + l16) * 128 + ((c0 ^ l16) << 3);
            bf16x8 b1 = *(const bf16x8*)&ws1[brow];
            bf16x8 b2 = *(const bf16x8*)&ws2[brow];
            acc[jt] = __builtin_amdgcn_mfma_f32_16x16x32_bf16(a1, b1, acc[jt], 0, 0, 0);
            acc[jt] = __builtin_amdgcn_mfma_f32_16x16x32_bf16(a2, b2, acc[jt], 0, 0, 0);
        }
    }
#pragma unroll
    for (int reg = 0; reg < 4; reg++) {
        int node = base + wave * 16 + quad * 4 + reg;
        if (node >= N_NODES) continue;
#pragma unroll
        for (int jt = 0; jt < 8; jt++) {
            int col = jt * 16 + l16;
            out[(size_t)node * D + col] = acc[jt][reg] + brel[col];
        }
    }
}

extern "C" void kernel_launch(void* const* d_in, const int* in_sizes, int n_in,
                              void* d_out, int out_size, void* d_ws, size_t ws_size,
                              hipStream_t stream) {
    const float* x     = (const float*)d_in[0];
    const int*   ei    = (const int*)d_in[1];
    const int*   et    = (const int*)d_in[2];
    const float* basis = (const float*)d_in[3];
    const float* comp  = (const float*)d_in[4];
    const float* root  = (const float*)d_in[5];
    const float* bias1 = (const float*)d_in[6];
    const float* wrel  = (const float*)d_in[7];
    const float* brel  = (const float*)d_in[8];
    const float* wroot = (const float*)d_in[9];
    float* out = (float*)d_out;
    const int* src = ei;
    const int* dst = ei + E_EDGES;

    char* p = (char*)d_ws;
    auto alloc = [&](size_t bytes) { char* q = p; p += (bytes + 255) & ~(size_t)255; return q; };
    short* wt      = (short*)alloc((size_t)R_REL * D * D * sizeof(short));
    short* root_t  = (short*)alloc(D * D * sizeof(short));
    short* wrel_b  = (short*)alloc(D * D * sizeof(short));
    short* wroot_b = (short*)alloc(D * D * sizeof(short));
    int*   cntr    = (int*)alloc((size_t)RN * sizeof(int));
    int*   seg_off = (int*)alloc((size_t)RN * sizeof(int));
    int*   cur     = (int*)alloc((size_t)RN * sizeof(int));
    int*   es1     = (int*)alloc((size_t)(E_EDGES + 16) * sizeof(int));
    int*   bsum    = (int*)alloc(SCAN_B * sizeof(int));
    unsigned short* xb   = (unsigned short*)alloc((size_t)N_NODES * D * sizeof(unsigned short));
    unsigned short* ybig = (unsigned short*)alloc((size_t)4 * N_NODES * D * sizeof(unsigned short));
    float* h1      = (float*)alloc((size_t)N_NODES * D * sizeof(float));
    unsigned short* h1b  = (unsigned short*)alloc((size_t)N_NODES * D * sizeof(unsigned short));
    unsigned short* nbr  = xb;   // xb dead after root GEMM; reuse for nbr

    hipMemsetAsync(cntr, 0, (size_t)RN * sizeof(int), stream);
    hipMemsetAsync(cur,  0, (size_t)RN * sizeof(int), stream);

    k_prep<<<(R_REL * D * D + D * D + 255) / 256, 256, 0, stream>>>(
        basis, comp, root, wrel, wroot, wt, root_t, wrel_b, wroot_b);
    k_x2b<<<(N_NODES * D / 8 + 255) / 256, 256, 0, stream>>>(x, xb);
    k_count<<<(E_EDGES + 255) / 256, 256, 0, stream>>>(dst, et, cntr);

    int nscan = (RN + SCAN_B - 1) / SCAN_B;
    k_scan_a<<<nscan, SCAN_B, 0, stream>>>(cntr, seg_off, bsum, RN);
    k_scan_b<<<1, SCAN_B, 0, stream>>>(bsum, nscan);
    k_scan_c<<<nscan, SCAN_B, 0, stream>>>(seg_off, bsum, RN);

    k_bucket<<<(E_EDGES + 255) / 256, 256, 0, stream>>>(src, dst, et, seg_off, cur, es1);

    int nb = (N_NODES + 63) / 64;     // 782
    int na = (N_NODES + 3) / 4;       // 12500

    k_ygemm<<<dim3(nb, 4), 256, 0, stream>>>(xb, wt, 0, ybig);
    k_agg4<<<na, 256, 0, stream>>>(ybig, es1, cntr, seg_off, h1, 0, 0);
    k_ygemm<<<dim3(nb, 4), 256, 0, stream>>>(xb, wt, 4, ybig);
    k_agg4<<<na, 256, 0, stream>>>(ybig, es1, cntr, seg_off, h1, 4, 1);

    // h1b = bf16(agg + x@root + bias1)
    k_gemm_root<<<nb, 256, 0, stream>>>(xb, root_t, bias1, h1, h1b);
    // nbr = sum h1b[src]  (writes into xb buffer)
    k_agg_nbr<<<na, 256, 0, stream>>>(h1b, es1, cntr, seg_off, nbr);
    // out = h1b@wroot^T + nbr@wrel^T + brel
    k_out2<<<nb, 256, 0, stream>>>(h1b, nbr, wroot_b, wrel_b, brel, out);
}

// Round 4
// 325.468 us; speedup vs baseline: 4.6860x; 1.3286x over previous
//
#include <hip/hip_runtime.h>
#include <stdint.h>

#define N_NODES 50000
#define E_EDGES 600000
#define D 128
#define R_REL 8
#define B_BASES 10
#define RN (R_REL * N_NODES)
#define SCAN_B 1024

typedef __attribute__((ext_vector_type(8))) short bf16x8;
typedef __attribute__((ext_vector_type(4))) float f32x4;

__device__ __forceinline__ short f2b(float f) {
    uint32_t u = __float_as_uint(f);
    u += 0x7fff + ((u >> 16) & 1);   // RNE
    return (short)(u >> 16);
}
__device__ __forceinline__ float b2f(uint16_t u) {
    return __uint_as_float((uint32_t)u << 16);
}

// ---- fused weight prep ----
__global__ __launch_bounds__(256) void k_prep(const float* __restrict__ basis,
                                              const float* __restrict__ comp,
                                              const float* __restrict__ root,
                                              const float* __restrict__ wrel,
                                              const float* __restrict__ wroot,
                                              short* __restrict__ wt,
                                              short* __restrict__ root_t,
                                              short* __restrict__ wrel_b,
                                              short* __restrict__ wroot_b) {
    int tid = blockIdx.x * 256 + threadIdx.x;
    if (tid < R_REL * D * D) {
        int r = tid >> 14;
        int rem = tid & 16383;
        int j = rem >> 7, i = rem & 127;
        float s = 0.f;
#pragma unroll
        for (int b = 0; b < B_BASES; b++)
            s += comp[r * B_BASES + b] * basis[b * D * D + i * D + j];
        wt[tid] = f2b(s);
    } else {
        int t2 = tid - R_REL * D * D;
        if (t2 < D * D) {
            int j = t2 >> 7, i = t2 & 127;
            root_t[t2]  = f2b(root[i * D + j]);
            wrel_b[t2]  = f2b(wrel[t2]);
            wroot_b[t2] = f2b(wroot[t2]);
        }
    }
}

// ---- x (fp32) -> xb (bf16) ----
__global__ __launch_bounds__(256) void k_x2b(const float* __restrict__ x,
                                             unsigned short* __restrict__ xb) {
    int tid = blockIdx.x * 256 + threadIdx.x;
    if (tid >= N_NODES * D / 8) return;
    const float4* s = (const float4*)x + (size_t)tid * 2;
    float4 v0 = s[0], v1 = s[1];
    union { uint4 u; unsigned short h[8]; } pk;
    pk.h[0] = (unsigned short)f2b(v0.x); pk.h[1] = (unsigned short)f2b(v0.y);
    pk.h[2] = (unsigned short)f2b(v0.z); pk.h[3] = (unsigned short)f2b(v0.w);
    pk.h[4] = (unsigned short)f2b(v1.x); pk.h[5] = (unsigned short)f2b(v1.y);
    pk.h[6] = (unsigned short)f2b(v1.z); pk.h[7] = (unsigned short)f2b(v1.w);
    ((uint4*)xb)[tid] = pk.u;
}

// ---- histogram per (dst, rel) — dst-major key ----
__global__ __launch_bounds__(256) void k_count(const int* __restrict__ dst,
                                               const int* __restrict__ et,
                                               int* __restrict__ cntr) {
    int e = blockIdx.x * 256 + threadIdx.x;
    if (e >= E_EDGES) return;
    atomicAdd(&cntr[dst[e] * R_REL + et[e]], 1);
}

// ---- 3-kernel exclusive scan ----
__global__ __launch_bounds__(SCAN_B) void k_scan_a(const int* __restrict__ in,
                                                   int* __restrict__ out,
                                                   int* __restrict__ bsum, int n) {
    __shared__ int lds[SCAN_B];
    int t = threadIdx.x, g = blockIdx.x * SCAN_B + t;
    int v = (g < n) ? in[g] : 0;
    lds[t] = v;
    __syncthreads();
    for (int off = 1; off < SCAN_B; off <<= 1) {
        int tv = (t >= off) ? lds[t - off] : 0;
        __syncthreads();
        lds[t] += tv;
        __syncthreads();
    }
    if (g < n) out[g] = lds[t] - v;
    if (t == SCAN_B - 1) bsum[blockIdx.x] = lds[t];
}

__global__ __launch_bounds__(SCAN_B) void k_scan_b(int* __restrict__ bsum, int nb) {
    __shared__ int lds[SCAN_B];
    int t = threadIdx.x;
    int v = (t < nb) ? bsum[t] : 0;
    lds[t] = v;
    __syncthreads();
    for (int off = 1; off < SCAN_B; off <<= 1) {
        int tv = (t >= off) ? lds[t - off] : 0;
        __syncthreads();
        lds[t] += tv;
        __syncthreads();
    }
    if (t < nb) bsum[t] = lds[t] - v;
}

__global__ __launch_bounds__(SCAN_B) void k_scan_c(int* __restrict__ out,
                                                   const int* __restrict__ bsum, int n) {
    int g = blockIdx.x * SCAN_B + threadIdx.x;
    if (g < n) out[g] += bsum[blockIdx.x];
}

// ---- bucket edges into (dst, rel)-sorted order ----
__global__ __launch_bounds__(256) void k_bucket(const int* __restrict__ src,
                                                const int* __restrict__ dst,
                                                const int* __restrict__ et,
                                                const int* __restrict__ seg_off,
                                                int* __restrict__ cur,
                                                int* __restrict__ es1) {
    int e = blockIdx.x * 256 + threadIdx.x;
    if (e >= E_EDGES) return;
    int key = dst[e] * R_REL + et[e];
    int pos = seg_off[key] + atomicAdd(&cur[key], 1);
    es1[pos] = src[e];
}

// ---- batched per-relation GEMM: ybig[slice] = xb @ W_{r0+slice} ----
__global__ __launch_bounds__(256) void k_ygemm(const unsigned short* __restrict__ xb,
                                               const short* __restrict__ wt, int r0,
                                               unsigned short* __restrict__ ybig) {
    __shared__ short xs[64 * 128];
    __shared__ short ws[128 * 128];
    int slice = blockIdx.y;
    const short* w = wt + (size_t)(r0 + slice) * D * D;
    unsigned short* y = ybig + (size_t)slice * N_NODES * D;
    int base = blockIdx.x * 64;
    int t = threadIdx.x;
    const uint4* wsrc = (const uint4*)w;
    for (int idx = t; idx < 2048; idx += 256) {
        int j = idx >> 4, c = idx & 15;
        *(uint4*)&ws[j * 128 + ((c ^ (j & 15)) << 3)] = wsrc[idx];
    }
    for (int idx = t; idx < 1024; idx += 256) {
        int row = idx >> 4, c = idx & 15;
        int node = base + row;
        uint4 v = make_uint4(0, 0, 0, 0);
        if (node < N_NODES) v = ((const uint4*)(xb + (size_t)node * D))[c];
        *(uint4*)&xs[row * 128 + ((c ^ (row & 15)) << 3)] = v;
    }
    __syncthreads();

    int wave = t >> 6, lane = t & 63, quad = lane >> 4, l16 = lane & 15;
    f32x4 acc[8];
#pragma unroll
    for (int jt = 0; jt < 8; jt++) acc[jt] = (f32x4){0.f, 0.f, 0.f, 0.f};
#pragma unroll
    for (int kc = 0; kc < 4; kc++) {
        int c0 = kc * 4 + quad;
        bf16x8 a = *(const bf16x8*)&xs[(wave * 16 + l16) * 128 + ((c0 ^ l16) << 3)];
#pragma unroll
        for (int jt = 0; jt < 8; jt++) {
            bf16x8 b = *(const bf16x8*)&ws[(jt * 16 + l16) * 128 + ((c0 ^ l16) << 3)];
            acc[jt] = __builtin_amdgcn_mfma_f32_16x16x32_bf16(a, b, acc[jt], 0, 0, 0);
        }
    }
#pragma unroll
    for (int reg = 0; reg < 4; reg++) {
        int node = base + wave * 16 + quad * 4 + reg;
        if (node >= N_NODES) continue;
#pragma unroll
        for (int jt = 0; jt < 8; jt++)
            y[(size_t)node * D + jt * 16 + l16] = (unsigned short)f2b(acc[jt][reg]);
    }
}

// ---- root transform: h1b = bf16(x@root + bias1 + h1) ----
__global__ __launch_bounds__(256) void k_gemm_root(const unsigned short* __restrict__ inb,
                                                   const short* __restrict__ bt,
                                                   const float* __restrict__ bias,
                                                   const float* __restrict__ prev,
                                                   unsigned short* __restrict__ outb) {
    __shared__ short xs[64 * 128];
    __shared__ short ws[128 * 128];
    int base = blockIdx.x * 64;
    int t = threadIdx.x;
    const uint4* wsrc = (const uint4*)bt;
    for (int idx = t; idx < 2048; idx += 256) {
        int j = idx >> 4, c = idx & 15;
        *(uint4*)&ws[j * 128 + ((c ^ (j & 15)) << 3)] = wsrc[idx];
    }
    for (int idx = t; idx < 1024; idx += 256) {
        int row = idx >> 4, c = idx & 15;
        int node = base + row;
        uint4 v = make_uint4(0, 0, 0, 0);
        if (node < N_NODES) v = ((const uint4*)(inb + (size_t)node * D))[c];
        *(uint4*)&xs[row * 128 + ((c ^ (row & 15)) << 3)] = v;
    }
    __syncthreads();

    int wave = t >> 6, lane = t & 63, quad = lane >> 4, l16 = lane & 15;
    f32x4 acc[8];
#pragma unroll
    for (int jt = 0; jt < 8; jt++) acc[jt] = (f32x4){0.f, 0.f, 0.f, 0.f};
#pragma unroll
    for (int kc = 0; kc < 4; kc++) {
        int c0 = kc * 4 + quad;
        bf16x8 a = *(const bf16x8*)&xs[(wave * 16 + l16) * 128 + ((c0 ^ l16) << 3)];
#pragma unroll
        for (int jt = 0; jt < 8; jt++) {
            bf16x8 b = *(const bf16x8*)&ws[(jt * 16 + l16) * 128 + ((c0 ^ l16) << 3)];
            acc[jt] = __builtin_amdgcn_mfma_f32_16x16x32_bf16(a, b, acc[jt], 0, 0, 0);
        }
    }
#pragma unroll
    for (int reg = 0; reg < 4; reg++) {
        int node = base + wave * 16 + quad * 4 + reg;
        if (node >= N_NODES) continue;
#pragma unroll
        for (int jt = 0; jt < 8; jt++) {
            int col = jt * 16 + l16;
            float v = acc[jt][reg] + bias[col] + prev[(size_t)node * D + col];
            outb[(size_t)node * D + col] = (unsigned short)f2b(v);
        }
    }
}

// ---- RGCN agg, 4 relations/phase: 16-lane sub-wave per dst, flat contiguous loop ----
__global__ __launch_bounds__(256) void k_agg4(const unsigned short* __restrict__ y,
                                              const int* __restrict__ es1,
                                              const int* __restrict__ cntr,
                                              const int* __restrict__ seg_off,
                                              float* __restrict__ h1, int phase) {
    int t = threadIdx.x;
    int wave = t >> 6, lane = t & 63, sub = lane >> 4, l = lane & 15;
    int d = blockIdx.x * 16 + wave * 4 + sub;
    if (d >= N_NODES) return;
    int kb = d * R_REL + phase * 4;
    int b0 = seg_off[kb], b1 = seg_off[kb + 1], b2 = seg_off[kb + 2], b3 = seg_off[kb + 3];
    int c3 = cntr[kb + 3];
    int end = b3 + c3;
    int c0 = b1 - b0, c1 = b2 - b1, c2 = b3 - b2;
    float n0 = c0 ? 1.f / (float)c0 : 0.f;
    float n1 = c1 ? 1.f / (float)c1 : 0.f;
    float n2 = c2 ? 1.f / (float)c2 : 0.f;
    float n3 = c3 ? 1.f / (float)c3 : 0.f;

    float acc[8];
#pragma unroll
    for (int j = 0; j < 8; j++) acc[j] = 0.f;
    size_t loff = (size_t)l * 8;

    int pos = b0;
    for (; pos + 4 <= end; pos += 4) {
        int i0 = es1[pos], i1 = es1[pos + 1], i2 = es1[pos + 2], i3 = es1[pos + 3];
        float m0 = (pos     >= b1) ? ((pos     >= b3) ? n3 : (pos     >= b2) ? n2 : n1) : n0;
        float m1 = (pos + 1 >= b1) ? ((pos + 1 >= b3) ? n3 : (pos + 1 >= b2) ? n2 : n1) : n0;
        float m2 = (pos + 2 >= b1) ? ((pos + 2 >= b3) ? n3 : (pos + 2 >= b2) ? n2 : n1) : n0;
        float m3 = (pos + 3 >= b1) ? ((pos + 3 >= b3) ? n3 : (pos + 3 >= b2) ? n2 : n1) : n0;
        int r0 = (pos     >= b1) + (pos     >= b2) + (pos     >= b3);
        int r1 = (pos + 1 >= b1) + (pos + 1 >= b2) + (pos + 1 >= b3);
        int r2 = (pos + 2 >= b1) + (pos + 2 >= b2) + (pos + 2 >= b3);
        int r3 = (pos + 3 >= b1) + (pos + 3 >= b2) + (pos + 3 >= b3);
        uint4 v0 = *(const uint4*)(y + ((size_t)r0 * N_NODES + i0) * D + loff);
        uint4 v1 = *(const uint4*)(y + ((size_t)r1 * N_NODES + i1) * D + loff);
        uint4 v2 = *(const uint4*)(y + ((size_t)r2 * N_NODES + i2) * D + loff);
        uint4 v3 = *(const uint4*)(y + ((size_t)r3 * N_NODES + i3) * D + loff);
        const uint32_t* w0 = (const uint32_t*)&v0;
        const uint32_t* w1 = (const uint32_t*)&v1;
        const uint32_t* w2 = (const uint32_t*)&v2;
        const uint32_t* w3 = (const uint32_t*)&v3;
#pragma unroll
        for (int q = 0; q < 4; q++) {
            acc[q * 2]     += m0 * b2f((uint16_t)w0[q]) + m1 * b2f((uint16_t)w1[q]) +
                              m2 * b2f((uint16_t)w2[q]) + m3 * b2f((uint16_t)w3[q]);
            acc[q * 2 + 1] += m0 * b2f((uint16_t)(w0[q] >> 16)) + m1 * b2f((uint16_t)(w1[q] >> 16)) +
                              m2 * b2f((uint16_t)(w2[q] >> 16)) + m3 * b2f((uint16_t)(w3[q] >> 16));
        }
    }
    for (; pos < end; pos++) {
        int i0 = es1[pos];
        float m0 = (pos >= b1) ? ((pos >= b3) ? n3 : (pos >= b2) ? n2 : n1) : n0;
        int r0 = (pos >= b1) + (pos >= b2) + (pos >= b3);
        uint4 v0 = *(const uint4*)(y + ((size_t)r0 * N_NODES + i0) * D + loff);
        const uint32_t* w0 = (const uint32_t*)&v0;
#pragma unroll
        for (int q = 0; q < 4; q++) {
            acc[q * 2]     += m0 * b2f((uint16_t)w0[q]);
            acc[q * 2 + 1] += m0 * b2f((uint16_t)(w0[q] >> 16));
        }
    }

    float* hr = h1 + (size_t)d * D + loff;
    if (phase) {
#pragma unroll
        for (int j = 0; j < 8; j++) acc[j] += hr[j];
    }
    *(float4*)hr = make_float4(acc[0], acc[1], acc[2], acc[3]);
    *(float4*)(hr + 4) = make_float4(acc[4], acc[5], acc[6], acc[7]);
}

// ---- GraphConv agg: nbr[d] = sum over full in-edge range of h1b[src] ----
__global__ __launch_bounds__(256) void k_agg_nbr(const unsigned short* __restrict__ h1b,
                                                 const int* __restrict__ es1,
                                                 const int* __restrict__ seg_off,
                                                 unsigned short* __restrict__ nbr) {
    int t = threadIdx.x;
    int wave = t >> 6, lane = t & 63, sub = lane >> 4, l = lane & 15;
    int d = blockIdx.x * 16 + wave * 4 + sub;
    if (d >= N_NODES) return;
    int s0 = seg_off[d * R_REL];
    int end = (d == N_NODES - 1) ? E_EDGES : seg_off[(d + 1) * R_REL];
    float acc[8];
#pragma unroll
    for (int j = 0; j < 8; j++) acc[j] = 0.f;
    size_t loff = (size_t)l * 8;

    int pos = s0;
    for (; pos + 4 <= end; pos += 4) {
        int i0 = es1[pos], i1 = es1[pos + 1], i2 = es1[pos + 2], i3 = es1[pos + 3];
        uint4 v0 = *(const uint4*)(h1b + (size_t)i0 * D + loff);
        uint4 v1 = *(const uint4*)(h1b + (size_t)i1 * D + loff);
        uint4 v2 = *(const uint4*)(h1b + (size_t)i2 * D + loff);
        uint4 v3 = *(const uint4*)(h1b + (size_t)i3 * D + loff);
        const uint32_t* w0 = (const uint32_t*)&v0;
        const uint32_t* w1 = (const uint32_t*)&v1;
        const uint32_t* w2 = (const uint32_t*)&v2;
        const uint32_t* w3 = (const uint32_t*)&v3;
#pragma unroll
        for (int q = 0; q < 4; q++) {
            acc[q * 2]     += b2f((uint16_t)w0[q]) + b2f((uint16_t)w1[q]) +
                              b2f((uint16_t)w2[q]) + b2f((uint16_t)w3[q]);
            acc[q * 2 + 1] += b2f((uint16_t)(w0[q] >> 16)) + b2f((uint16_t)(w1[q] >> 16)) +
                              b2f((uint16_t)(w2[q] >> 16)) + b2f((uint16_t)(w3[q] >> 16));
        }
    }
    for (; pos < end; pos++) {
        int i0 = es1[pos];
        uint4 v0 = *(const uint4*)(h1b + (size_t)i0 * D + loff);
        const uint32_t* w0 = (const uint32_t*)&v0;
#pragma unroll
        for (int q = 0; q < 4; q++) {
            acc[q * 2]     += b2f((uint16_t)w0[q]);
            acc[q * 2 + 1] += b2f((uint16_t)(w0[q] >> 16));
        }
    }

    union { uint4 u; unsigned short h[8]; } pk;
#pragma unroll
    for (int j = 0; j < 8; j++) pk.h[j] = (unsigned short)f2b(acc[j]);
    *(uint4*)(nbr + (size_t)d * D + loff) = pk.u;
}

// ---- fused epilogue: out = h1b @ wroot^T + nbr @ wrel^T + brel ----
__global__ __launch_bounds__(256) void k_out2(const unsigned short* __restrict__ h1b,
                                              const unsigned short* __restrict__ nbr,
                                              const short* __restrict__ wroot_b,
                                              const short* __restrict__ wrel_b,
                                              const float* __restrict__ brel,
                                              float* __restrict__ out) {
    __shared__ short xs1[64 * 128];
    __shared__ short xs2[64 * 128];
    __shared__ short ws1[128 * 128];
    __shared__ short ws2[128 * 128];
    int base = blockIdx.x * 64;
    int t = threadIdx.x;
    const uint4* w1 = (const uint4*)wroot_b;
    const uint4* w2 = (const uint4*)wrel_b;
    for (int idx = t; idx < 2048; idx += 256) {
        int j = idx >> 4, c = idx & 15;
        int sw = j * 128 + ((c ^ (j & 15)) << 3);
        *(uint4*)&ws1[sw] = w1[idx];
        *(uint4*)&ws2[sw] = w2[idx];
    }
    for (int idx = t; idx < 1024; idx += 256) {
        int row = idx >> 4, c = idx & 15;
        int node = base + row;
        uint4 v1 = make_uint4(0, 0, 0, 0), v2 = make_uint4(0, 0, 0, 0);
        if (node < N_NODES) {
            v1 = ((const uint4*)(h1b + (size_t)node * D))[c];
            v2 = ((const uint4*)(nbr + (size_t)node * D))[c];
        }
        int sw = row * 128 + ((c ^ (row & 15)) << 3);
        *(uint4*)&xs1[sw] = v1;
        *(uint4*)&xs2[sw] = v2;
    }
    __syncthreads();

    int wave = t >> 6, lane = t & 63, quad = lane >> 4, l16 = lane & 15;
    f32x4 acc[8];
#pragma unroll
    for (int jt = 0; jt < 8; jt++) acc[jt] = (f32x4){0.f, 0.f, 0.f, 0.f};
#pragma unroll
    for (int kc = 0; kc < 4; kc++) {
        int c0 = kc * 4 + quad;
        int arow = (wave * 16 + l16) * 128 + ((c0 ^ l16) << 3);
        bf16x8 a1 = *(const bf16x8*)&xs1[arow];
        bf16x8 a2 = *(const bf16x8*)&xs2[arow];
#pragma unroll
        for (int jt = 0; jt < 8; jt++) {
            int brow = (jt * 16 + l16) * 128 + ((c0 ^ l16) << 3);
            bf16x8 b1 = *(const bf16x8*)&ws1[brow];
            bf16x8 b2 = *(const bf16x8*)&ws2[brow];
            acc[jt] = __builtin_amdgcn_mfma_f32_16x16x32_bf16(a1, b1, acc[jt], 0, 0, 0);
            acc[jt] = __builtin_amdgcn_mfma_f32_16x16x32_bf16(a2, b2, acc[jt], 0, 0, 0);
        }
    }
#pragma unroll
    for (int reg = 0; reg < 4; reg++) {
        int node = base + wave * 16 + quad * 4 + reg;
        if (node >= N_NODES) continue;
#pragma unroll
        for (int jt = 0; jt < 8; jt++) {
            int col = jt * 16 + l16;
            out[(size_t)node * D + col] = acc[jt][reg] + brel[col];
        }
    }
}

extern "C" void kernel_launch(void* const* d_in, const int* in_sizes, int n_in,
                              void* d_out, int out_size, void* d_ws, size_t ws_size,
                              hipStream_t stream) {
    const float* x     = (const float*)d_in[0];
    const int*   ei    = (const int*)d_in[1];
    const int*   et    = (const int*)d_in[2];
    const float* basis = (const float*)d_in[3];
    const float* comp  = (const float*)d_in[4];
    const float* root  = (const float*)d_in[5];
    const float* bias1 = (const float*)d_in[6];
    const float* wrel  = (const float*)d_in[7];
    const float* brel  = (const float*)d_in[8];
    const float* wroot = (const float*)d_in[9];
    float* out = (float*)d_out;
    const int* src = ei;
    const int* dst = ei + E_EDGES;

    char* p = (char*)d_ws;
    auto alloc = [&](size_t bytes) { char* q = p; p += (bytes + 255) & ~(size_t)255; return q; };
    short* wt      = (short*)alloc((size_t)R_REL * D * D * sizeof(short));
    short* root_t  = (short*)alloc(D * D * sizeof(short));
    short* wrel_b  = (short*)alloc(D * D * sizeof(short));
    short* wroot_b = (short*)alloc(D * D * sizeof(short));
    int*   cntr    = (int*)alloc((size_t)2 * RN * sizeof(int));   // cntr + cur adjacent
    int*   cur     = cntr + RN;
    int*   seg_off = (int*)alloc((size_t)RN * sizeof(int));
    int*   es1     = (int*)alloc((size_t)(E_EDGES + 16) * sizeof(int));
    int*   bsum    = (int*)alloc(SCAN_B * sizeof(int));
    unsigned short* xb   = (unsigned short*)alloc((size_t)N_NODES * D * sizeof(unsigned short));
    unsigned short* ybig = (unsigned short*)alloc((size_t)4 * N_NODES * D * sizeof(unsigned short));
    float* h1      = (float*)alloc((size_t)N_NODES * D * sizeof(float));
    unsigned short* h1b  = (unsigned short*)alloc((size_t)N_NODES * D * sizeof(unsigned short));
    unsigned short* nbr  = xb;   // xb dead after root GEMM; reuse for nbr

    hipMemsetAsync(cntr, 0, (size_t)2 * RN * sizeof(int), stream);

    k_prep<<<(R_REL * D * D + D * D + 255) / 256, 256, 0, stream>>>(
        basis, comp, root, wrel, wroot, wt, root_t, wrel_b, wroot_b);
    k_x2b<<<(N_NODES * D / 8 + 255) / 256, 256, 0, stream>>>(x, xb);
    k_count<<<(E_EDGES + 255) / 256, 256, 0, stream>>>(dst, et, cntr);

    int nscan = (RN + SCAN_B - 1) / SCAN_B;
    k_scan_a<<<nscan, SCAN_B, 0, stream>>>(cntr, seg_off, bsum, RN);
    k_scan_b<<<1, SCAN_B, 0, stream>>>(bsum, nscan);
    k_scan_c<<<nscan, SCAN_B, 0, stream>>>(seg_off, bsum, RN);

    k_bucket<<<(E_EDGES + 255) / 256, 256, 0, stream>>>(src, dst, et, seg_off, cur, es1);

    int nb = (N_NODES + 63) / 64;     // 782
    int na = (N_NODES + 15) / 16;     // 3125

    k_ygemm<<<dim3(nb, 4), 256, 0, stream>>>(xb, wt, 0, ybig);
    k_agg4<<<na, 256, 0, stream>>>(ybig, es1, cntr, seg_off, h1, 0);
    k_ygemm<<<dim3(nb, 4), 256, 0, stream>>>(xb, wt, 4, ybig);
    k_agg4<<<na, 256, 0, stream>>>(ybig, es1, cntr, seg_off, h1, 1);

    // h1b = bf16(agg + x@root + bias1)
    k_gemm_root<<<nb, 256, 0, stream>>>(xb, root_t, bias1, h1, h1b);
    // nbr = sum h1b[src]
    k_agg_nbr<<<na, 256, 0, stream>>>(h1b, es1, seg_off, nbr);
    // out = h1b@wroot^T + nbr@wrel^T + brel
    k_out2<<<nb, 256, 0, stream>>>(h1b, nbr, wroot_b, wrel_b, brel, out);
}

// Round 5
// 287.414 us; speedup vs baseline: 5.3065x; 1.1324x over previous
//
#include <hip/hip_runtime.h>
#include <stdint.h>

#define N_NODES 50000
#define E_EDGES 600000
#define D 128
#define R_REL 8
#define B_BASES 10
#define RN (R_REL * N_NODES)

typedef __attribute__((ext_vector_type(8))) short bf16x8;
typedef __attribute__((ext_vector_type(4))) float f32x4;

__device__ __forceinline__ short f2b(float f) {
    uint32_t u = __float_as_uint(f);
    u += 0x7fff + ((u >> 16) & 1);   // RNE
    return (short)(u >> 16);
}
__device__ __forceinline__ float b2f(uint16_t u) {
    return __uint_as_float((uint32_t)u << 16);
}

// ---- weight prep: wt[0..7]=relation mats (B-layout), wt[8]=root^T, + wrel/wroot ----
__global__ __launch_bounds__(256) void k_prep(const float* __restrict__ basis,
                                              const float* __restrict__ comp,
                                              const float* __restrict__ root,
                                              const float* __restrict__ wrel,
                                              const float* __restrict__ wroot,
                                              short* __restrict__ wt,
                                              short* __restrict__ wrel_b,
                                              short* __restrict__ wroot_b) {
    int tid = blockIdx.x * 256 + threadIdx.x;
    if (tid < 9 * D * D) {
        int s = tid >> 14;
        int rem = tid & 16383;
        int j = rem >> 7, i = rem & 127;
        float v;
        if (s < 8) {
            v = 0.f;
#pragma unroll
            for (int b = 0; b < B_BASES; b++)
                v += comp[s * B_BASES + b] * basis[b * D * D + i * D + j];
        } else {
            v = root[i * D + j];
        }
        wt[tid] = f2b(v);
    } else {
        int t2 = tid - 9 * D * D;
        if (t2 < D * D) {
            wrel_b[t2]  = f2b(wrel[t2]);
            wroot_b[t2] = f2b(wroot[t2]);
        }
    }
}

// ---- fused: x->bf16 convert + (dst,rel) histogram ----
__global__ __launch_bounds__(256) void k_misc(const float* __restrict__ x,
                                              unsigned short* __restrict__ xb,
                                              const int* __restrict__ dst,
                                              const int* __restrict__ et,
                                              int* __restrict__ cntr) {
    int tid = blockIdx.x * 256 + threadIdx.x;
    if (tid < N_NODES * D / 8) {
        const float4* s = (const float4*)x + (size_t)tid * 2;
        float4 v0 = s[0], v1 = s[1];
        union { uint4 u; unsigned short h[8]; } pk;
        pk.h[0] = (unsigned short)f2b(v0.x); pk.h[1] = (unsigned short)f2b(v0.y);
        pk.h[2] = (unsigned short)f2b(v0.z); pk.h[3] = (unsigned short)f2b(v0.w);
        pk.h[4] = (unsigned short)f2b(v1.x); pk.h[5] = (unsigned short)f2b(v1.y);
        pk.h[6] = (unsigned short)f2b(v1.z); pk.h[7] = (unsigned short)f2b(v1.w);
        ((uint4*)xb)[tid] = pk.u;
    } else {
        int e = tid - N_NODES * D / 8;
        if (e < E_EDGES)
            atomicAdd(&cntr[dst[e] * R_REL + et[e]], 1);
    }
}

// ---- shuffle-based block scan (1024 thr); doubles as level-2 when bsum==null ----
__device__ __forceinline__ int wave_scan_incl(int v) {
    int lane = threadIdx.x & 63;
#pragma unroll
    for (int off = 1; off < 64; off <<= 1) {
        int n = __shfl_up(v, off, 64);
        if (lane >= off) v += n;
    }
    return v;
}

__global__ __launch_bounds__(1024) void k_scan_a(const int* __restrict__ in,
                                                 int* __restrict__ out,
                                                 int* __restrict__ bsum, int n) {
    __shared__ int wsum[16];
    int t = threadIdx.x, lane = t & 63, wid = t >> 6;
    int g = blockIdx.x * 1024 + t;
    int v = (g < n) ? in[g] : 0;
    int isc = wave_scan_incl(v);
    if (lane == 63) wsum[wid] = isc;
    __syncthreads();
    if (wid == 0) {
        int wv = (lane < 16) ? wsum[lane] : 0;
        int wsc = wave_scan_incl(wv);
        if (lane < 16) wsum[lane] = wsc - wv;
    }
    __syncthreads();
    if (g < n) out[g] = wsum[wid] + isc - v;
    if (t == 1023 && bsum) bsum[blockIdx.x] = wsum[15] + isc;
}

__global__ __launch_bounds__(1024) void k_scan_c(int* __restrict__ out,
                                                 const int* __restrict__ bsum, int n) {
    int g = blockIdx.x * 1024 + threadIdx.x;
    if (g < n) out[g] += bsum[blockIdx.x];
}

// ---- bucket: es1 = src*8+rel (sorted by dst,rel), enorm = 1/cnt; bumps seg_off ----
__global__ __launch_bounds__(256) void k_bucket(const int* __restrict__ src,
                                                const int* __restrict__ dst,
                                                const int* __restrict__ et,
                                                const int* __restrict__ cntr,
                                                int* __restrict__ seg_off,
                                                int* __restrict__ es1,
                                                float* __restrict__ enorm) {
    int e = blockIdx.x * 256 + threadIdx.x;
    if (e >= E_EDGES) return;
    int r = et[e];
    int key = dst[e] * R_REL + r;
    int pos = atomicAdd(&seg_off[key], 1);
    es1[pos] = (src[e] << 3) | r;
    enorm[pos] = 1.0f / (float)cntr[key];
}

// ---- batched GEMM: ybig[slice] = xb @ wt[slice], slices 0..8 (8 = root) ----
__global__ __launch_bounds__(256) void k_ygemm(const unsigned short* __restrict__ xb,
                                               const short* __restrict__ wt,
                                               unsigned short* __restrict__ ybig) {
    __shared__ short xs[64 * 128];
    __shared__ short ws[128 * 128];
    int slice = blockIdx.y;
    const short* w = wt + (size_t)slice * D * D;
    unsigned short* y = ybig + (size_t)slice * N_NODES * D;
    int base = blockIdx.x * 64;
    int t = threadIdx.x;
    const uint4* wsrc = (const uint4*)w;
    for (int idx = t; idx < 2048; idx += 256) {
        int j = idx >> 4, c = idx & 15;
        *(uint4*)&ws[j * 128 + ((c ^ (j & 15)) << 3)] = wsrc[idx];
    }
    for (int idx = t; idx < 1024; idx += 256) {
        int row = idx >> 4, c = idx & 15;
        int node = base + row;
        uint4 v = make_uint4(0, 0, 0, 0);
        if (node < N_NODES) v = ((const uint4*)(xb + (size_t)node * D))[c];
        *(uint4*)&xs[row * 128 + ((c ^ (row & 15)) << 3)] = v;
    }
    __syncthreads();

    int wave = t >> 6, lane = t & 63, quad = lane >> 4, l16 = lane & 15;
    f32x4 acc[8];
#pragma unroll
    for (int jt = 0; jt < 8; jt++) acc[jt] = (f32x4){0.f, 0.f, 0.f, 0.f};
#pragma unroll
    for (int kc = 0; kc < 4; kc++) {
        int c0 = kc * 4 + quad;
        bf16x8 a = *(const bf16x8*)&xs[(wave * 16 + l16) * 128 + ((c0 ^ l16) << 3)];
#pragma unroll
        for (int jt = 0; jt < 8; jt++) {
            bf16x8 b = *(const bf16x8*)&ws[(jt * 16 + l16) * 128 + ((c0 ^ l16) << 3)];
            acc[jt] = __builtin_amdgcn_mfma_f32_16x16x32_bf16(a, b, acc[jt], 0, 0, 0);
        }
    }
#pragma unroll
    for (int reg = 0; reg < 4; reg++) {
        int node = base + wave * 16 + quad * 4 + reg;
        if (node >= N_NODES) continue;
#pragma unroll
        for (int jt = 0; jt < 8; jt++)
            y[(size_t)node * D + jt * 16 + l16] = (unsigned short)f2b(acc[jt][reg]);
    }
}

// ---- RGCN agg (all 8 rel) + root slice + bias -> h1b bf16.  16-lane sub-wave/node ----
// NOTE: seg_off was bumped by k_bucket: seg_off[k] now == original seg_off[k+1].
__global__ __launch_bounds__(256) void k_agg8(const unsigned short* __restrict__ ybig,
                                              const int* __restrict__ es1,
                                              const float* __restrict__ enorm,
                                              const int* __restrict__ seg_off,
                                              const float* __restrict__ bias1,
                                              unsigned short* __restrict__ h1b) {
    int t = threadIdx.x;
    int wave = t >> 6, lane = t & 63, sub = lane >> 4, l = lane & 15;
    int d = blockIdx.x * 16 + wave * 4 + sub;
    if (d >= N_NODES) return;
    int start = (d == 0) ? 0 : seg_off[d * R_REL - 1];
    int end = seg_off[d * R_REL + 7];
    float acc[8];
#pragma unroll
    for (int j = 0; j < 8; j++) acc[j] = 0.f;
    size_t loff = (size_t)l * 8;

    int pos = start;
    for (; pos + 4 <= end; pos += 4) {
        int p0 = es1[pos], p1 = es1[pos + 1], p2 = es1[pos + 2], p3 = es1[pos + 3];
        float m0 = enorm[pos], m1 = enorm[pos + 1], m2 = enorm[pos + 2], m3 = enorm[pos + 3];
        uint4 v0 = *(const uint4*)(ybig + ((size_t)(p0 & 7) * N_NODES + (p0 >> 3)) * D + loff);
        uint4 v1 = *(const uint4*)(ybig + ((size_t)(p1 & 7) * N_NODES + (p1 >> 3)) * D + loff);
        uint4 v2 = *(const uint4*)(ybig + ((size_t)(p2 & 7) * N_NODES + (p2 >> 3)) * D + loff);
        uint4 v3 = *(const uint4*)(ybig + ((size_t)(p3 & 7) * N_NODES + (p3 >> 3)) * D + loff);
        const uint32_t* w0 = (const uint32_t*)&v0;
        const uint32_t* w1 = (const uint32_t*)&v1;
        const uint32_t* w2 = (const uint32_t*)&v2;
        const uint32_t* w3 = (const uint32_t*)&v3;
#pragma unroll
        for (int q = 0; q < 4; q++) {
            acc[q * 2]     += m0 * b2f((uint16_t)w0[q]) + m1 * b2f((uint16_t)w1[q]) +
                              m2 * b2f((uint16_t)w2[q]) + m3 * b2f((uint16_t)w3[q]);
            acc[q * 2 + 1] += m0 * b2f((uint16_t)(w0[q] >> 16)) + m1 * b2f((uint16_t)(w1[q] >> 16)) +
                              m2 * b2f((uint16_t)(w2[q] >> 16)) + m3 * b2f((uint16_t)(w3[q] >> 16));
        }
    }
    for (; pos < end; pos++) {
        int p0 = es1[pos];
        float m0 = enorm[pos];
        uint4 v0 = *(const uint4*)(ybig + ((size_t)(p0 & 7) * N_NODES + (p0 >> 3)) * D + loff);
        const uint32_t* w0 = (const uint32_t*)&v0;
#pragma unroll
        for (int q = 0; q < 4; q++) {
            acc[q * 2]     += m0 * b2f((uint16_t)w0[q]);
            acc[q * 2 + 1] += m0 * b2f((uint16_t)(w0[q] >> 16));
        }
    }

    // + (x@root)[d] + bias1  -> h1b
    uint4 rv = *(const uint4*)(ybig + ((size_t)8 * N_NODES + d) * D + loff);
    const uint32_t* rw = (const uint32_t*)&rv;
    float4 ba = *(const float4*)(bias1 + l * 8);
    float4 bb = *(const float4*)(bias1 + l * 8 + 4);
    float bv[8] = {ba.x, ba.y, ba.z, ba.w, bb.x, bb.y, bb.z, bb.w};
    union { uint4 u; unsigned short h[8]; } pk;
#pragma unroll
    for (int q = 0; q < 4; q++) {
        pk.h[q * 2]     = (unsigned short)f2b(acc[q * 2] + b2f((uint16_t)rw[q]) + bv[q * 2]);
        pk.h[q * 2 + 1] = (unsigned short)f2b(acc[q * 2 + 1] + b2f((uint16_t)(rw[q] >> 16)) + bv[q * 2 + 1]);
    }
    *(uint4*)(h1b + (size_t)d * D + loff) = pk.u;
}

// ---- GraphConv agg: nbr[d] = sum h1b[src] over full in-edge range ----
__global__ __launch_bounds__(256) void k_agg_nbr(const unsigned short* __restrict__ h1b,
                                                 const int* __restrict__ es1,
                                                 const int* __restrict__ seg_off,
                                                 unsigned short* __restrict__ nbr) {
    int t = threadIdx.x;
    int wave = t >> 6, lane = t & 63, sub = lane >> 4, l = lane & 15;
    int d = blockIdx.x * 16 + wave * 4 + sub;
    if (d >= N_NODES) return;
    int start = (d == 0) ? 0 : seg_off[d * R_REL - 1];
    int end = seg_off[d * R_REL + 7];
    float acc[8];
#pragma unroll
    for (int j = 0; j < 8; j++) acc[j] = 0.f;
    size_t loff = (size_t)l * 8;

    int pos = start;
    for (; pos + 4 <= end; pos += 4) {
        int i0 = es1[pos] >> 3, i1 = es1[pos + 1] >> 3;
        int i2 = es1[pos + 2] >> 3, i3 = es1[pos + 3] >> 3;
        uint4 v0 = *(const uint4*)(h1b + (size_t)i0 * D + loff);
        uint4 v1 = *(const uint4*)(h1b + (size_t)i1 * D + loff);
        uint4 v2 = *(const uint4*)(h1b + (size_t)i2 * D + loff);
        uint4 v3 = *(const uint4*)(h1b + (size_t)i3 * D + loff);
        const uint32_t* w0 = (const uint32_t*)&v0;
        const uint32_t* w1 = (const uint32_t*)&v1;
        const uint32_t* w2 = (const uint32_t*)&v2;
        const uint32_t* w3 = (const uint32_t*)&v3;
#pragma unroll
        for (int q = 0; q < 4; q++) {
            acc[q * 2]     += b2f((uint16_t)w0[q]) + b2f((uint16_t)w1[q]) +
                              b2f((uint16_t)w2[q]) + b2f((uint16_t)w3[q]);
            acc[q * 2 + 1] += b2f((uint16_t)(w0[q] >> 16)) + b2f((uint16_t)(w1[q] >> 16)) +
                              b2f((uint16_t)(w2[q] >> 16)) + b2f((uint16_t)(w3[q] >> 16));
        }
    }
    for (; pos < end; pos++) {
        int i0 = es1[pos] >> 3;
        uint4 v0 = *(const uint4*)(h1b + (size_t)i0 * D + loff);
        const uint32_t* w0 = (const uint32_t*)&v0;
#pragma unroll
        for (int q = 0; q < 4; q++) {
            acc[q * 2]     += b2f((uint16_t)w0[q]);
            acc[q * 2 + 1] += b2f((uint16_t)(w0[q] >> 16));
        }
    }

    union { uint4 u; unsigned short h[8]; } pk;
#pragma unroll
    for (int j = 0; j < 8; j++) pk.h[j] = (unsigned short)f2b(acc[j]);
    *(uint4*)(nbr + (size_t)d * D + loff) = pk.u;
}

// ---- fused epilogue: out = h1b @ wroot^T + nbr @ wrel^T + brel ----
__global__ __launch_bounds__(256) void k_out2(const unsigned short* __restrict__ h1b,
                                              const unsigned short* __restrict__ nbr,
                                              const short* __restrict__ wroot_b,
                                              const short* __restrict__ wrel_b,
                                              const float* __restrict__ brel,
                                              float* __restrict__ out) {
    __shared__ short xs1[64 * 128];
    __shared__ short xs2[64 * 128];
    __shared__ short ws1[128 * 128];
    __shared__ short ws2[128 * 128];
    int base = blockIdx.x * 64;
    int t = threadIdx.x;
    const uint4* w1 = (const uint4*)wroot_b;
    const uint4* w2 = (const uint4*)wrel_b;
    for (int idx = t; idx < 2048; idx += 256) {
        int j = idx >> 4, c = idx & 15;
        int sw = j * 128 + ((c ^ (j & 15)) << 3);
        *(uint4*)&ws1[sw] = w1[idx];
        *(uint4*)&ws2[sw] = w2[idx];
    }
    for (int idx = t; idx < 1024; idx += 256) {
        int row = idx >> 4, c = idx & 15;
        int node = base + row;
        uint4 v1 = make_uint4(0, 0, 0, 0), v2 = make_uint4(0, 0, 0, 0);
        if (node < N_NODES) {
            v1 = ((const uint4*)(h1b + (size_t)node * D))[c];
            v2 = ((const uint4*)(nbr + (size_t)node * D))[c];
        }
        int sw = row * 128 + ((c ^ (row & 15)) << 3);
        *(uint4*)&xs1[sw] = v1;
        *(uint4*)&xs2[sw] = v2;
    }
    __syncthreads();

    int wave = t >> 6, lane = t & 63, quad = lane >> 4, l16 = lane & 15;
    f32x4 acc[8];
#pragma unroll
    for (int jt = 0; jt < 8; jt++) acc[jt] = (f32x4){0.f, 0.f, 0.f, 0.f};
#pragma unroll
    for (int kc = 0; kc < 4; kc++) {
        int c0 = kc * 4 + quad;
        int arow = (wave * 16 + l16) * 128 + ((c0 ^ l16) << 3);
        bf16x8 a1 = *(const bf16x8*)&xs1[arow];
        bf16x8 a2 = *(const bf16x8*)&xs2[arow];
#pragma unroll
        for (int jt = 0; jt < 8; jt++) {
            int brow = (jt * 16 + l16) * 128 + ((c0 ^ l16) << 3);
            bf16x8 b1 = *(const bf16x8*)&ws1[brow];
            bf16x8 b2 = *(const bf16x8*)&ws2[brow];
            acc[jt] = __builtin_amdgcn_mfma_f32_16x16x32_bf16(a1, b1, acc[jt], 0, 0, 0);
            acc[jt] = __builtin_amdgcn_mfma_f32_16x16x32_bf16(a2, b2, acc[jt], 0, 0, 0);
        }
    }
#pragma unroll
    for (int reg = 0; reg < 4; reg++) {
        int node = base + wave * 16 + quad * 4 + reg;
        if (node >= N_NODES) continue;
#pragma unroll
        for (int jt = 0; jt < 8; jt++) {
            int col = jt * 16 + l16;
            out[(size_t)node * D + col] = acc[jt][reg] + brel[col];
        }
    }
}

extern "C" void kernel_launch(void* const* d_in, const int* in_sizes, int n_in,
                              void* d_out, int out_size, void* d_ws, size_t ws_size,
                              hipStream_t stream) {
    const float* x     = (const float*)d_in[0];
    const int*   ei    = (const int*)d_in[1];
    const int*   et    = (const int*)d_in[2];
    const float* basis = (const float*)d_in[3];
    const float* comp  = (const float*)d_in[4];
    const float* root  = (const float*)d_in[5];
    const float* bias1 = (const float*)d_in[6];
    const float* wrel  = (const float*)d_in[7];
    const float* brel  = (const float*)d_in[8];
    const float* wroot = (const float*)d_in[9];
    float* out = (float*)d_out;
    const int* src = ei;
    const int* dst = ei + E_EDGES;

    char* p = (char*)d_ws;
    auto alloc = [&](size_t bytes) { char* q = p; p += (bytes + 255) & ~(size_t)255; return q; };
    short* wt      = (short*)alloc((size_t)9 * D * D * sizeof(short));
    short* wrel_b  = (short*)alloc(D * D * sizeof(short));
    short* wroot_b = (short*)alloc(D * D * sizeof(short));
    int*   cntr    = (int*)alloc((size_t)RN * sizeof(int));
    int*   seg_off = (int*)alloc((size_t)RN * sizeof(int));
    int*   es1     = (int*)alloc((size_t)(E_EDGES + 16) * sizeof(int));
    float* enorm   = (float*)alloc((size_t)(E_EDGES + 16) * sizeof(float));
    int*   bsum    = (int*)alloc(1024 * sizeof(int));
    unsigned short* xb   = (unsigned short*)alloc((size_t)N_NODES * D * sizeof(unsigned short));
    unsigned short* ybig = (unsigned short*)alloc((size_t)9 * N_NODES * D * sizeof(unsigned short));
    unsigned short* h1b  = (unsigned short*)alloc((size_t)N_NODES * D * sizeof(unsigned short));
    unsigned short* nbr  = xb;   // xb dead after k_ygemm; reuse for nbr

    hipMemsetAsync(cntr, 0, (size_t)RN * sizeof(int), stream);

    k_prep<<<(9 * D * D + D * D + 255) / 256, 256, 0, stream>>>(
        basis, comp, root, wrel, wroot, wt, wrel_b, wroot_b);
    k_misc<<<(N_NODES * D / 8 + E_EDGES + 255) / 256, 256, 0, stream>>>(x, xb, dst, et, cntr);

    int nscan = (RN + 1023) / 1024;   // 391
    k_scan_a<<<nscan, 1024, 0, stream>>>(cntr, seg_off, bsum, RN);
    k_scan_a<<<1, 1024, 0, stream>>>(bsum, bsum, nullptr, nscan);
    k_scan_c<<<nscan, 1024, 0, stream>>>(seg_off, bsum, RN);

    k_bucket<<<(E_EDGES + 255) / 256, 256, 0, stream>>>(src, dst, et, cntr, seg_off, es1, enorm);

    int nb = (N_NODES + 63) / 64;     // 782
    int na = (N_NODES + 15) / 16;     // 3125

    k_ygemm<<<dim3(nb, 9), 256, 0, stream>>>(xb, wt, ybig);
    k_agg8<<<na, 256, 0, stream>>>(ybig, es1, enorm, seg_off, bias1, h1b);
    k_agg_nbr<<<na, 256, 0, stream>>>(h1b, es1, seg_off, nbr);
    k_out2<<<nb, 256, 0, stream>>>(h1b, nbr, wroot_b, wrel_b, brel, out);
}